// Round 2
// baseline (2662.545 us; speedup 1.0000x reference)
//
#include <hip/hip_runtime.h>
#include <hip/hip_bf16.h>
#include <stdint.h>

typedef __hip_bfloat16 bf16;

// Problem constants (hardcoded from reference)
constexpr int B_  = 8;
constexpr int PQ_ = 900;
constexpr int C_  = 256;
constexpr int NH_ = 8;
constexpr int L_  = 4;
constexpr int P_  = 4;
constexpr int FF_ = 2048;
constexpr int DH_ = C_ / NH_;   // 32
constexpr int PK_ = 20197;      // 100*152 + 50*76 + 25*38 + 13*19

__device__ __forceinline__ float ldf(const float* p) { return *p; }
__device__ __forceinline__ float ldf(const bf16*  p) { return __bfloat162float(*p); }
__device__ __forceinline__ void  stf(float* p, float v) { *p = v; }
__device__ __forceinline__ void  stf(bf16*  p, float v) { *p = __float2bfloat16(v); }

// ---------------------------------------------------------------------------
// Generic tiled GEMM:  C[b*Mb+m, n] = act( sum_k A[m,k] * W[n,k] + bias[n] )
//   TRANS_A=false: A is (nb*Mb, K) row-major (nb must be 1); ldA/colOff unused
//   TRANS_A=true : A[m=(b,ml), k] = A[((int64_t)b*K + k)*ldA + colOff + ml]
// ---------------------------------------------------------------------------
template <typename TA, typename TC, bool TRANS_A, bool RELU>
__launch_bounds__(256)
__global__ void gemm_kernel(const TA* __restrict__ A, const float* __restrict__ W,
                            const float* __restrict__ bias, TC* __restrict__ Cout,
                            int Mb, int N, int K, int tilesM, int ldA, int colOff)
{
    constexpr int BM = 64, BN = 64, BK = 16;
    __shared__ float As[BK][BM + 1];
    __shared__ float Bs[BK][BN + 1];

    const int tid = threadIdx.x;
    const int b   = blockIdx.y / tilesM;
    const int m0  = (blockIdx.y % tilesM) * BM;
    const int n0  = blockIdx.x * BN;
    const int tx  = tid & 15;
    const int ty  = tid >> 4;

    float acc[4][4] = {};

    for (int k0 = 0; k0 < K; k0 += BK) {
        __syncthreads();
        // --- stage A tile ---
#pragma unroll
        for (int u = 0; u < (BM * BK) / 256; ++u) {
            int li = u * 256 + tid;
            if (TRANS_A) {
                int r  = li & (BM - 1);   // m (contiguous in memory)
                int kk = li >> 6;
                int ml = m0 + r;
                float v = 0.f;
                if (ml < Mb) v = ldf(&A[((int64_t)b * K + (k0 + kk)) * ldA + colOff + ml]);
                As[kk][r] = v;
            } else {
                int kk = li & (BK - 1);   // k (contiguous in memory)
                int r  = li >> 4;
                int ml = m0 + r;
                float v = 0.f;
                if (ml < Mb) v = ldf(&A[((int64_t)(b * Mb + ml)) * K + k0 + kk]);
                As[kk][r] = v;
            }
        }
        // --- stage W tile (W is (N,K) row-major, fp32) ---
#pragma unroll
        for (int u = 0; u < (BN * BK) / 256; ++u) {
            int li = u * 256 + tid;
            int kk = li & (BK - 1);
            int r  = li >> 4;
            int nn = n0 + r;
            Bs[kk][r] = (nn < N) ? W[(int64_t)nn * K + k0 + kk] : 0.f;
        }
        __syncthreads();
        // --- compute ---
#pragma unroll
        for (int kk = 0; kk < BK; ++kk) {
            float av[4], bv[4];
#pragma unroll
            for (int i = 0; i < 4; ++i) { av[i] = As[kk][ty * 4 + i]; bv[i] = Bs[kk][tx * 4 + i]; }
#pragma unroll
            for (int i = 0; i < 4; ++i)
#pragma unroll
                for (int j = 0; j < 4; ++j) acc[i][j] += av[i] * bv[j];
        }
    }

    // --- epilogue ---
#pragma unroll
    for (int i = 0; i < 4; ++i) {
        int ml = m0 + ty * 4 + i;
        if (ml >= Mb) continue;
        int64_t rowoff = (int64_t)(b * Mb + ml) * N;
#pragma unroll
        for (int j = 0; j < 4; ++j) {
            int nn = n0 + tx * 4 + j;
            if (nn < N) {
                float v = acc[i][j] + bias[nn];
                if (RELU) v = fmaxf(v, 0.f);
                stf(&Cout[rowoff + nn], v);
            }
        }
    }
}

template <typename TA, typename TC, bool TRANS_A, bool RELU>
static void launch_gemm(const TA* A, const float* W, const float* bias, TC* Cout,
                        int nb, int Mb, int N, int K, hipStream_t stream,
                        int ldA = 0, int colOff = 0)
{
    int tilesM = (Mb + 63) / 64;
    dim3 grid((N + 63) / 64, nb * tilesM);
    gemm_kernel<TA, TC, TRANS_A, RELU><<<grid, 256, 0, stream>>>(A, W, bias, Cout, Mb, N, K,
                                                                 tilesM, ldA, colOff);
}

// ---------------------------------------------------------------------------
// Fused MHA: per (b, h, q-tile of 12) with full score row in LDS.
// qkv layout: (B*PQ, 768), q = [0,256), k = [256,512), v = [512,768)
// ---------------------------------------------------------------------------
constexpr int ATQ = 12;   // 900 = 75 * 12, exact
constexpr int AKT = 64;

__launch_bounds__(256)
__global__ void attn_kernel(const float* __restrict__ qkv, float* __restrict__ o)
{
    const int b   = blockIdx.x / NH_;
    const int h   = blockIdx.x % NH_;
    const int q0  = blockIdx.y * ATQ;
    const int tid = threadIdx.x;

    __shared__ float S[ATQ][PQ_];        // 43.2 KB
    __shared__ float Qs[ATQ][DH_ + 1];
    __shared__ float KV[AKT][DH_ + 1];
    __shared__ float red[ATQ][17];
    __shared__ float rowM[ATQ], rowS[ATQ];

    // load Q tile
    for (int li = tid; li < ATQ * DH_; li += 256) {
        int qi = li >> 5, d = li & 31;
        Qs[qi][d] = qkv[(int64_t)(b * PQ_ + q0 + qi) * 768 + h * DH_ + d];
    }

    const float scale = 0.17677669529663687f;  // 1/sqrt(32)

    // phase 1: scores
    for (int kt0 = 0; kt0 < PQ_; kt0 += AKT) {
        const int kn = min(AKT, PQ_ - kt0);
        __syncthreads();
        for (int li = tid; li < AKT * DH_; li += 256) {
            int r = li >> 5, d = li & 31;
            KV[r][d] = (r < kn) ? qkv[(int64_t)(b * PQ_ + kt0 + r) * 768 + 256 + h * DH_ + d] : 0.f;
        }
        __syncthreads();
        for (int li = tid; li < ATQ * AKT; li += 256) {
            int qi = li >> 6, r = li & 63;
            if (r < kn) {
                float s = 0.f;
#pragma unroll
                for (int d = 0; d < DH_; ++d) s += Qs[qi][d] * KV[r][d];
                S[qi][kt0 + r] = s * scale;
            }
        }
    }
    __syncthreads();

    // softmax over each row (16 workers per row)
    const int row = tid >> 4;
    const int w16 = tid & 15;
    if (row < ATQ) {
        float mx = -1e30f;
        for (int k = w16; k < PQ_; k += 16) mx = fmaxf(mx, S[row][k]);
        red[row][w16] = mx;
    }
    __syncthreads();
    if (row < ATQ && w16 == 0) {
        float m = red[row][0];
        for (int i = 1; i < 16; ++i) m = fmaxf(m, red[row][i]);
        rowM[row] = m;
    }
    __syncthreads();
    if (row < ATQ) {
        float m = rowM[row], sm = 0.f;
        for (int k = w16; k < PQ_; k += 16) {
            float e = __expf(S[row][k] - m);
            S[row][k] = e;
            sm += e;
        }
        red[row][w16] = sm;
    }
    __syncthreads();
    if (row < ATQ && w16 == 0) {
        float s = 0.f;
        for (int i = 0; i < 16; ++i) s += red[row][i];
        rowS[row] = s;
    }
    __syncthreads();

    // phase 2: O = P @ V.  thread -> (d = tid&31, g = tid>>5); rows g and g+8 (g<4)
    const int d = tid & 31, g = tid >> 5;
    float acc0 = 0.f, acc1 = 0.f;
    for (int kt0 = 0; kt0 < PQ_; kt0 += AKT) {
        const int kn = min(AKT, PQ_ - kt0);
        __syncthreads();
        for (int li = tid; li < AKT * DH_; li += 256) {
            int r = li >> 5, dd = li & 31;
            KV[r][dd] = (r < kn) ? qkv[(int64_t)(b * PQ_ + kt0 + r) * 768 + 512 + h * DH_ + dd] : 0.f;
        }
        __syncthreads();
        for (int r = 0; r < kn; ++r) {
            float v = KV[r][d];
            acc0 += S[g][kt0 + r] * v;
            if (g < 4) acc1 += S[g + 8][kt0 + r] * v;
        }
    }
    o[(int64_t)(b * PQ_ + q0 + g) * C_ + h * DH_ + d] = acc0 / rowS[g];
    if (g < 4)
        o[(int64_t)(b * PQ_ + q0 + g + 8) * C_ + h * DH_ + d] = acc1 / rowS[g + 8];
}

// ---------------------------------------------------------------------------
// Residual + LayerNorm over C=256.
// MODE 0: residual read transposed from query (B,C,PQ); out (B*PQ,C) fp32
// MODE 1: residual fp32 (B*PQ,C); out fp32 (B*PQ,C)
// MODE 2: residual fp32 (B*PQ,C); out transposed fp32 (B,C,PQ)  [final output]
// ---------------------------------------------------------------------------
template <int MODE>
__launch_bounds__(256)
__global__ void ln_kernel(const float* __restrict__ y, const float* __restrict__ res,
                          const float* __restrict__ g, const float* __restrict__ be,
                          float* __restrict__ outp)
{
    const int bt = blockIdx.x;
    const int b  = bt / PQ_, t = bt % PQ_;
    const int c  = threadIdx.x;

    float r;
    if (MODE == 0) r = res[((int64_t)b * C_ + c) * PQ_ + t];
    else           r = res[(int64_t)bt * C_ + c];
    float v = r + y[(int64_t)bt * C_ + c];

    __shared__ float s1[256], s2[256];
    s1[c] = v;
    s2[c] = v * v;
    __syncthreads();
    for (int st = 128; st > 0; st >>= 1) {
        if (c < st) { s1[c] += s1[c + st]; s2[c] += s2[c + st]; }
        __syncthreads();
    }
    float mean = s1[0] * (1.f / C_);
    float var  = s2[0] * (1.f / C_) - mean * mean;
    float outv = (v - mean) * rsqrtf(var + 1e-5f) * g[c] + be[c];

    if (MODE == 2) outp[((int64_t)b * C_ + c) * PQ_ + t] = outv;
    else           outp[(int64_t)bt * C_ + c] = outv;
}

// ---------------------------------------------------------------------------
// Fused MS-deformable sampling for ONE level, accumulating into samp.
// One block per (b, q); thread -> (h=tid>>5, d=tid&31).
// value_l: (B, Hl*Wl, NH, DH) bf16 for this level only.
// offb: (B*PQ, 256); awl: (B*PQ, 128); refp: (B,PQ,L,2)
// INIT=true  -> samp = acc (level 0)
// INIT=false -> samp += acc (levels 1..3)
// ---------------------------------------------------------------------------
template <bool INIT>
__launch_bounds__(256)
__global__ void deform_level_kernel(const float* __restrict__ offb, const float* __restrict__ awl,
                                    const float* __restrict__ refp, const bf16* __restrict__ value_l,
                                    float* __restrict__ samp, int l, int Hl, int Wl)
{
    const int bt  = blockIdx.x;
    const int b   = bt / PQ_;
    const int tid = threadIdx.x;
    const int h   = tid >> 5, d = tid & 31;

    __shared__ float Loff[64];   // this level's offsets: [h][p][xy] = 8 per head
    __shared__ float Law[128];   // all logits (needed for softmax denominator)
    __shared__ float Lref[2];

    if (tid < 64) {
        int hh = tid >> 3, r = tid & 7;  // r = p*2+xy
        Loff[tid] = offb[(int64_t)bt * 256 + hh * 32 + l * 8 + r];
    }
    if (tid < 128) Law[tid] = awl[(int64_t)bt * 128 + tid];
    if (tid < 2)   Lref[tid] = refp[(int64_t)bt * 8 + l * 2 + tid];
    __syncthreads();

    // softmax stats for this head over all L*P=16 logits (redundant across lanes)
    float m = -1e30f;
#pragma unroll
    for (int i = 0; i < 16; ++i) m = fmaxf(m, Law[h * 16 + i]);
    float s = 0.f;
#pragma unroll
    for (int i = 0; i < 16; ++i) s += __expf(Law[h * 16 + i] - m);
    const float invs = 1.f / s;

    const float fx = Lref[0], fy = Lref[1];
    const int HW = Hl * Wl;

    float acc = 0.f;
#pragma unroll
    for (int p = 0; p < P_; ++p) {
        float ox = Loff[h * 8 + p * 2 + 0];
        float oy = Loff[h * 8 + p * 2 + 1];
        float x = (fx + ox / (float)Wl) * (float)Wl - 0.5f;
        float y = (fy + oy / (float)Hl) * (float)Hl - 0.5f;
        float x0f = floorf(x), y0f = floorf(y);
        int   x0 = (int)x0f, y0 = (int)y0f;
        float lw = x - x0f, lh = y - y0f;
        float w00 = (1.f - lw) * (1.f - lh);
        float w10 = lw * (1.f - lh);
        float w01 = (1.f - lw) * lh;
        float w11 = lw * lh;
        float aww = __expf(Law[h * 16 + l * 4 + p] - m) * invs;

        float sv = 0.f;
        int ix, iy; float w;
#pragma unroll
        for (int cidx = 0; cidx < 4; ++cidx) {
            if (cidx == 0) { ix = x0;     iy = y0;     w = w00; }
            if (cidx == 1) { ix = x0 + 1; iy = y0;     w = w10; }
            if (cidx == 2) { ix = x0;     iy = y0 + 1; w = w01; }
            if (cidx == 3) { ix = x0 + 1; iy = y0 + 1; w = w11; }
            bool valid = (ix >= 0) && (ix < Wl) && (iy >= 0) && (iy < Hl);
            if (valid) {
                int64_t vi = (((int64_t)b * HW + iy * Wl + ix) * NH_ + h) * DH_ + d;
                sv += w * __bfloat162float(value_l[vi]);
            }
        }
        acc += sv * aww;
    }
    if (INIT) samp[(int64_t)bt * 256 + tid] = acc;
    else      samp[(int64_t)bt * 256 + tid] += acc;
}

// ---------------------------------------------------------------------------
extern "C" void kernel_launch(void* const* d_in, const int* in_sizes, int n_in,
                              void* d_out, int out_size, void* d_ws, size_t ws_size,
                              hipStream_t stream)
{
    const float* query = (const float*)d_in[0];   // (B, C, PQ)
    const float* key   = (const float*)d_in[1];   // (B, C, PK)
    const float* refp  = (const float*)d_in[4];   // (B, PQ, L, 2)
    const float* W_in  = (const float*)d_in[5];
    const float* b_in  = (const float*)d_in[6];
    const float* W_out = (const float*)d_in[7];
    const float* b_out = (const float*)d_in[8];
    const float* W_off = (const float*)d_in[9];
    const float* b_off = (const float*)d_in[10];
    const float* W_aw  = (const float*)d_in[11];
    const float* b_aw  = (const float*)d_in[12];
    const float* W_v   = (const float*)d_in[13];
    const float* b_v   = (const float*)d_in[14];
    const float* W_o   = (const float*)d_in[15];
    const float* b_o   = (const float*)d_in[16];
    const float* W1    = (const float*)d_in[17];
    const float* b1    = (const float*)d_in[18];
    const float* W2    = (const float*)d_in[19];
    const float* b2    = (const float*)d_in[20];
    const float* g1    = (const float*)d_in[21];
    const float* be1   = (const float*)d_in[22];
    const float* g2    = (const float*)d_in[23];
    const float* be2   = (const float*)d_in[24];
    const float* g3    = (const float*)d_in[25];
    const float* be3   = (const float*)d_in[26];

    // ------------------------------------------------------------------
    // Workspace plan (aliased by live range; peak ~84 MiB, was 197 MB
    // which overflowed ws_size and corrupted harness memory):
    //   R0 [0..62.3MB):   qkv(s1-2) -> value_l(s5-8, max level0) -> ffh(s11-12)
    //   R1: attno(s2-3) -> offb(s6-8) -> proj2(s9-10) -> ffo(s12-13)
    //   R2: proj(s3-4)  -> samp(s8-9) -> q2n(s10-13)
    //   R3: q1(s4-10)
    //   R4: awl(s7-8)
    // ------------------------------------------------------------------
    char* ws = (char*)d_ws;
    const size_t R0_SZ = (size_t)B_ * 15200 * C_ * 2;        // 62,259,200 (level-0 value, largest user)
    const size_t R1_SZ = (size_t)B_ * PQ_ * C_ * 4;          // 7,372,800
    const size_t R2_SZ = R1_SZ;
    const size_t R3_SZ = R1_SZ;
    char* R0 = ws;
    char* R1 = R0 + R0_SZ;
    char* R2 = R1 + R1_SZ;
    char* R3 = R2 + R2_SZ;
    char* R4 = R3 + R3_SZ;
    // total = 62.3MB + 3*7.37MB + 3.69MB ~= 88.1 MB <= ws_size (assumed)

    float* qkv   = (float*)R0;   // (B*PQ, 768) 22.1 MB
    bf16*  valL  = (bf16*) R0;   // per-level value, up to 62.3 MB
    bf16*  ffh   = (bf16*) R0;   // (B*PQ, FF) 29.5 MB
    float* attno = (float*)R1;
    float* offb  = (float*)R1;
    float* proj2 = (float*)R1;
    float* ffo   = (float*)R1;
    float* proj  = (float*)R2;
    float* samp  = (float*)R2;
    float* q2n   = (float*)R2;
    float* q1    = (float*)R3;
    float* awl   = (float*)R4;

    const int HL[4] = {100, 50, 25, 13};
    const int WL[4] = {152, 76, 38, 19};
    const int ST[4] = {0, 15200, 19000, 19950};

    // 1. qkv = x @ W_in^T + b_in   (x read transposed from query)
    launch_gemm<float, float, true, false>(query, W_in, b_in, qkv, B_, PQ_, 3 * C_, C_, stream, PQ_, 0);
    // 2. fused self-attention -> attno
    attn_kernel<<<dim3(B_ * NH_, PQ_ / ATQ), 256, 0, stream>>>(qkv, attno);
    // 3. out projection
    launch_gemm<float, float, false, false>(attno, W_out, b_out, proj, 1, B_ * PQ_, C_, C_, stream);
    // 4. q1 = LN(x + proj)
    ln_kernel<0><<<B_ * PQ_, 256, 0, stream>>>(proj, query, g1, be1, q1);
    // 5. sampling offsets (reads q1, writes R1 — attno dead)
    launch_gemm<float, float, false, false>(q1, W_off, b_off, offb, 1, B_ * PQ_, 256, C_, stream);
    // 6. attention-weight logits
    launch_gemm<float, float, false, false>(q1, W_aw, b_aw, awl, 1, B_ * PQ_, 128, C_, stream);
    // 7. per-level: value projection (into R0, qkv dead) + deform accumulate into samp (R2, proj dead)
    for (int l = 0; l < L_; ++l) {
        int HW = HL[l] * WL[l];
        launch_gemm<float, bf16, true, false>(key, W_v, b_v, valL, B_, HW, C_, C_, stream, PK_, ST[l]);
        if (l == 0)
            deform_level_kernel<true ><<<B_ * PQ_, 256, 0, stream>>>(offb, awl, refp, valL, samp, l, HL[l], WL[l]);
        else
            deform_level_kernel<false><<<B_ * PQ_, 256, 0, stream>>>(offb, awl, refp, valL, samp, l, HL[l], WL[l]);
    }
    // 8. output projection of sampled features (reads samp/R2, writes proj2/R1 — offb dead)
    launch_gemm<float, float, false, false>(samp, W_o, b_o, proj2, 1, B_ * PQ_, C_, C_, stream);
    // 9. q2n = LN(q1 + proj2)  (writes R2 — samp dead)
    ln_kernel<1><<<B_ * PQ_, 256, 0, stream>>>(proj2, q1, g2, be2, q2n);
    // 10. FFN up + ReLU (bf16 hidden into R0 — value dead)
    launch_gemm<float, bf16, false, true>(q2n, W1, b1, ffh, 1, B_ * PQ_, FF_, C_, stream);
    // 11. FFN down (writes ffo/R1 — proj2 dead)
    launch_gemm<bf16, float, false, false>(ffh, W2, b2, ffo, 1, B_ * PQ_, C_, FF_, stream);
    // 12. final LN + residual, written transposed to (B, C, PQ)
    ln_kernel<2><<<B_ * PQ_, 256, 0, stream>>>(ffo, q2n, g3, be3, (float*)d_out);

    (void)in_sizes; (void)n_in; (void)out_size; (void)ws_size;
}

// Round 3
// 1723.930 us; speedup vs baseline: 1.5445x; 1.5445x over previous
//
#include <hip/hip_runtime.h>
#include <hip/hip_bf16.h>
#include <stdint.h>

typedef __hip_bfloat16 bf16;
typedef short bf16x8 __attribute__((ext_vector_type(8)));
typedef short s4v    __attribute__((ext_vector_type(4)));
typedef float f32x4  __attribute__((ext_vector_type(4)));

constexpr int B_  = 8;
constexpr int PQ_ = 900;
constexpr int C_  = 256;
constexpr int NH_ = 8;
constexpr int L_  = 4;
constexpr int P_  = 4;
constexpr int FF_ = 2048;
constexpr int DH_ = 32;
constexpr int PK_ = 20197;
constexpr int SLD = 928;    // padded score row length (29*32)

__device__ __forceinline__ short f2b(float f) {
    __hip_bfloat16 h = __float2bfloat16(f);
    union { __hip_bfloat16 h; short s; } u; u.h = h; return u.s;
}
__device__ __forceinline__ float b2f(short s) {
    union { short s; __hip_bfloat16 h; } u; u.s = s; return __bfloat162float(u.h);
}

// ---------------------------------------------------------------------------
// Generalized batched MFMA GEMM.
// C[batch][m][n] = act( scale * sum_k A[batch][m][k] * W[batch][n][k] + bias[n] )
// A: fp32 or bf16 (AF32), k-contiguous, row stride ldA (elements)
// W: fp32 or bf16 (WF32), k-contiguous, row stride ldW
// batch = outer*nbI + inner; offsets offX = outer*sXo + inner*sXi (elements)
// Tile: BM=64, BN=256 (grid.x covers N), BK=32. 256 thr = 4 waves; wave w owns
// cols [64w,64w+64). mfma_f32_16x16x32_bf16; A-frag: m=lane&15,k=quad*8+j;
// C/D: col=lane&15, row=quad*4+reg  [per cdna_hip_programming.md §3].
// LDS rows padded to 40 shorts (80 B) -> frag ds_read_b128 conflict-free.
// ---------------------------------------------------------------------------
template <bool AF32, bool WF32, bool CF32, bool RELU>
__launch_bounds__(256)
__global__ void mfma_gemm(const void* __restrict__ Ap, const void* __restrict__ Wp,
                          const float* __restrict__ bias, void* __restrict__ Cp,
                          int Mb, int N, int K, int tilesM,
                          int ldA, int ldW, int ldC, int nbI,
                          int64_t sAo, int64_t sAi, int64_t sWo, int64_t sWi,
                          int64_t sCo, int64_t sCi, float scale)
{
    constexpr int LDR = 40;            // shorts per LDS row (32 + 8 pad)
    __shared__ short As[64 * LDR];     // 5.1 KB
    __shared__ short Ws[256 * LDR];    // 20.5 KB

    const int tid   = threadIdx.x;
    const int batch = blockIdx.y / tilesM;
    const int m0    = (blockIdx.y % tilesM) * 64;
    const int n0    = blockIdx.x * 256;
    const int outer = batch / nbI, inner = batch % nbI;
    const int64_t offA = (int64_t)outer * sAo + (int64_t)inner * sAi;
    const int64_t offW = (int64_t)outer * sWo + (int64_t)inner * sWi;
    const int64_t offC = (int64_t)outer * sCo + (int64_t)inner * sCi;

    const int w = tid >> 6, lane = tid & 63;
    const int quad = lane >> 4, lrow = lane & 15;
    const int nbase = n0 + w * 64;
    const bool activeW = (nbase < N);

    f32x4 acc[4][4] = {};

    for (int k0 = 0; k0 < K; k0 += 32) {
        // ---- stage A tile: 64 m x 32 k ----
        {
            const int m = tid >> 2, kq = (tid & 3) * 8;
            const int gm = m0 + m;
            bf16x8 pk = {0, 0, 0, 0, 0, 0, 0, 0};
            if (gm < Mb) {
                if (AF32) {
                    const float* src = (const float*)Ap + offA + (int64_t)gm * ldA + k0 + kq;
                    float4 u0 = *(const float4*)src;
                    float4 u1 = *(const float4*)(src + 4);
                    pk = (bf16x8){f2b(u0.x), f2b(u0.y), f2b(u0.z), f2b(u0.w),
                                  f2b(u1.x), f2b(u1.y), f2b(u1.z), f2b(u1.w)};
                } else {
                    pk = *(const bf16x8*)((const short*)Ap + offA + (int64_t)gm * ldA + k0 + kq);
                }
            }
            *(bf16x8*)&As[m * LDR + kq] = pk;
        }
        // ---- stage W tile: 256 n x 32 k ----
        if (WF32) {
#pragma unroll
            for (int p = 0; p < 8; ++p) {
                const int n = p * 32 + (tid >> 3);
                const int kq = (tid & 7) * 4;
                const int gn = n0 + n;
                float x0 = 0.f, x1 = 0.f, x2 = 0.f, x3 = 0.f;
                if (gn < N) {
                    float4 u = *(const float4*)((const float*)Wp + offW + (int64_t)gn * ldW + k0 + kq);
                    x0 = u.x; x1 = u.y; x2 = u.z; x3 = u.w;
                }
                s4v pk = {f2b(x0), f2b(x1), f2b(x2), f2b(x3)};
                *(s4v*)&Ws[n * LDR + kq] = pk;
            }
        } else {
#pragma unroll
            for (int p = 0; p < 4; ++p) {
                const int n = p * 64 + (tid >> 2);
                const int kq = (tid & 3) * 8;
                const int gn = n0 + n;
                bf16x8 pk = {0, 0, 0, 0, 0, 0, 0, 0};
                if (gn < N)
                    pk = *(const bf16x8*)((const short*)Wp + offW + (int64_t)gn * ldW + k0 + kq);
                *(bf16x8*)&Ws[n * LDR + kq] = pk;
            }
        }
        __syncthreads();
        if (activeW) {
            bf16x8 a[4], bb[4];
#pragma unroll
            for (int mf = 0; mf < 4; ++mf)
                a[mf] = *(const bf16x8*)&As[(mf * 16 + lrow) * LDR + quad * 8];
#pragma unroll
            for (int nf = 0; nf < 4; ++nf)
                bb[nf] = *(const bf16x8*)&Ws[(w * 64 + nf * 16 + lrow) * LDR + quad * 8];
#pragma unroll
            for (int mf = 0; mf < 4; ++mf)
#pragma unroll
                for (int nf = 0; nf < 4; ++nf)
                    acc[mf][nf] = __builtin_amdgcn_mfma_f32_16x16x32_bf16(a[mf], bb[nf], acc[mf][nf], 0, 0, 0);
        }
        __syncthreads();
    }

    if (!activeW) return;
#pragma unroll
    for (int nf = 0; nf < 4; ++nf) {
        const int col = nbase + nf * 16 + lrow;
        if (col >= N) continue;
        const float bia = bias ? bias[col] : 0.f;
#pragma unroll
        for (int mf = 0; mf < 4; ++mf) {
            const int row0 = m0 + mf * 16 + quad * 4;
#pragma unroll
            for (int r = 0; r < 4; ++r) {
                const int rr = row0 + r;
                if (rr < Mb) {
                    float v = acc[mf][nf][r] * scale + bia;
                    if (RELU) v = fmaxf(v, 0.f);
                    const int64_t idx = offC + (int64_t)rr * ldC + col;
                    if (CF32) ((float*)Cp)[idx] = v;
                    else      ((short*)Cp)[idx] = f2b(v);
                }
            }
        }
    }
}

template <bool AF32, bool WF32, bool CF32, bool RELU>
static void mfma_launch(const void* A, const void* W, const float* bias, void* Cp,
                        int nb, int nbI, int Mb, int N, int K,
                        int ldA, int ldW, int ldC,
                        int64_t sAo, int64_t sAi, int64_t sWo, int64_t sWi,
                        int64_t sCo, int64_t sCi, float scale, hipStream_t stream)
{
    int tilesM = (Mb + 63) / 64;
    dim3 grid((N + 255) / 256, nb * tilesM);
    mfma_gemm<AF32, WF32, CF32, RELU><<<grid, 256, 0, stream>>>(
        A, W, bias, Cp, Mb, N, K, tilesM, ldA, ldW, ldC, nbI,
        sAo, sAi, sWo, sWi, sCo, sCi, scale);
}

// ---------------------------------------------------------------------------
// 32x32 tile transpose: dst[b][s][c] (bf16, row=256) = src[b*sbs + (c0+c)*ldS + s]
// ---------------------------------------------------------------------------
__launch_bounds__(256)
__global__ void transpose_kernel(const float* __restrict__ src, short* __restrict__ dst,
                                 int Scount, int ldS, int64_t sbs, int64_t dbs)
{
    const int tid = threadIdx.x;
    const int b = blockIdx.z;
    const int s0 = blockIdx.x * 32, c0 = blockIdx.y * 32;
    __shared__ float t[32][33];
    {
        const int c_l = tid >> 3, sq = (tid & 7) * 4;
        const int64_t base = (int64_t)b * sbs + (int64_t)(c0 + c_l) * ldS;
#pragma unroll
        for (int i = 0; i < 4; ++i) {
            const int s = s0 + sq + i;
            t[c_l][sq + i] = (s < Scount) ? src[base + s] : 0.f;
        }
    }
    __syncthreads();
    {
        const int s_l = tid >> 3, cq = (tid & 7) * 4;
        const int s = s0 + s_l;
        if (s < Scount) {
            s4v pk = {f2b(t[cq + 0][s_l]), f2b(t[cq + 1][s_l]),
                      f2b(t[cq + 2][s_l]), f2b(t[cq + 3][s_l])};
            *(s4v*)&dst[(int64_t)b * dbs + (int64_t)s * 256 + c0 + cq] = pk;
        }
    }
}

// ---------------------------------------------------------------------------
// VT[bh][d][s] (bf16, ld=928, s>=900 zero) = qkv[(b*900+s)*768 + 512 + h*32 + d]
// ---------------------------------------------------------------------------
__launch_bounds__(256)
__global__ void vt_kernel(const float* __restrict__ qkv, short* __restrict__ VT)
{
    const int tid = threadIdx.x;
    const int bh = blockIdx.y, b = bh >> 3, h = bh & 7;
    const int s0 = blockIdx.x * 32;
    __shared__ float t[32][33];
    {
        const int s_l = tid >> 3, dq = (tid & 7) * 4;
        const int s = s0 + s_l;
        float x0 = 0.f, x1 = 0.f, x2 = 0.f, x3 = 0.f;
        if (s < 900) {
            float4 u = *(const float4*)&qkv[((int64_t)(b * 900 + s)) * 768 + 512 + h * 32 + dq];
            x0 = u.x; x1 = u.y; x2 = u.z; x3 = u.w;
        }
        t[s_l][dq + 0] = x0; t[s_l][dq + 1] = x1; t[s_l][dq + 2] = x2; t[s_l][dq + 3] = x3;
    }
    __syncthreads();
    {
        const int d = tid >> 3, sq = (tid & 7) * 4;
        s4v pk = {f2b(t[sq + 0][d]), f2b(t[sq + 1][d]), f2b(t[sq + 2][d]), f2b(t[sq + 3][d])};
        *(s4v*)&VT[(int64_t)bh * 32 * SLD + (int64_t)d * SLD + s0 + sq] = pk;
    }
}

// ---------------------------------------------------------------------------
// In-place row softmax over bf16 score rows (900 valid of 928; pads cols 900..927 = 0)
// ---------------------------------------------------------------------------
__launch_bounds__(256)
__global__ void softmax_kernel(short* __restrict__ S)
{
    const int tid = threadIdx.x;
    const int64_t base = (int64_t)blockIdx.x * SLD;
    float v[4];
    int idx[4] = {tid, tid + 256, tid + 512, tid + 768};
    float mx = -1e30f;
#pragma unroll
    for (int i = 0; i < 4; ++i) {
        if (idx[i] < 900) { v[i] = b2f(S[base + idx[i]]); mx = fmaxf(mx, v[i]); }
        else v[i] = -1e30f;
    }
    __shared__ float red[256];
    red[tid] = mx; __syncthreads();
    for (int st = 128; st > 0; st >>= 1) {
        if (tid < st) red[tid] = fmaxf(red[tid], red[tid + st]);
        __syncthreads();
    }
    const float m = red[0];
    __syncthreads();
    float sm = 0.f;
#pragma unroll
    for (int i = 0; i < 4; ++i)
        if (idx[i] < 900) { v[i] = __expf(v[i] - m); sm += v[i]; }
    red[tid] = sm; __syncthreads();
    for (int st = 128; st > 0; st >>= 1) {
        if (tid < st) red[tid] += red[tid + st];
        __syncthreads();
    }
    const float inv = 1.f / red[0];
#pragma unroll
    for (int i = 0; i < 4; ++i)
        if (idx[i] < 900) S[base + idx[i]] = f2b(v[i] * inv);
    if (tid < SLD - 900) S[base + 900 + tid] = 0;
}

// ---------------------------------------------------------------------------
// Residual + LayerNorm over C=256, one block per (b,t).
// MODE 0: res = query (B,C,PQ) fp32 transposed-read; out q1 fp32 + q1b bf16
// MODE 1: res = q1 fp32 (BT,C);                      out q2nb bf16 only
// MODE 2: res = q2nb bf16 (BT,C);                    out d_out fp32 (B,C,PQ)
// ---------------------------------------------------------------------------
template <int MODE>
__launch_bounds__(256)
__global__ void ln_kernel(const float* __restrict__ y, const void* __restrict__ res,
                          const float* __restrict__ g, const float* __restrict__ be,
                          float* __restrict__ out_f, short* __restrict__ out_b)
{
    const int bt = blockIdx.x;
    const int b = bt / PQ_, t = bt % PQ_;
    const int c = threadIdx.x;

    float r;
    if (MODE == 0)      r = ((const float*)res)[((int64_t)b * C_ + c) * PQ_ + t];
    else if (MODE == 1) r = ((const float*)res)[(int64_t)bt * C_ + c];
    else                r = b2f(((const short*)res)[(int64_t)bt * C_ + c]);
    const float v = r + y[(int64_t)bt * C_ + c];

    __shared__ float s1[256], s2[256];
    s1[c] = v; s2[c] = v * v;
    __syncthreads();
    for (int st = 128; st > 0; st >>= 1) {
        if (c < st) { s1[c] += s1[c + st]; s2[c] += s2[c + st]; }
        __syncthreads();
    }
    const float mean = s1[0] * (1.f / C_);
    const float var  = s2[0] * (1.f / C_) - mean * mean;
    const float o = (v - mean) * rsqrtf(var + 1e-5f) * g[c] + be[c];

    if (MODE == 0) { out_f[(int64_t)bt * C_ + c] = o; out_b[(int64_t)bt * C_ + c] = f2b(o); }
    else if (MODE == 1) out_b[(int64_t)bt * C_ + c] = f2b(o);
    else out_f[((int64_t)b * C_ + c) * PQ_ + t] = o;
}

// ---------------------------------------------------------------------------
// MS-deformable sampling for one level, accumulating into samp (bf16).
// value_l: (B, Hl*Wl, NH, DH) bf16. One block per (b,q); thread=(h=tid>>5,d=tid&31).
// ---------------------------------------------------------------------------
template <bool INIT>
__launch_bounds__(256)
__global__ void deform_level_kernel(const float* __restrict__ offb, const float* __restrict__ awl,
                                    const float* __restrict__ refp, const short* __restrict__ value_l,
                                    short* __restrict__ samp, int l, int Hl, int Wl)
{
    const int bt = blockIdx.x;
    const int b = bt / PQ_;
    const int tid = threadIdx.x;
    const int h = tid >> 5, d = tid & 31;

    __shared__ float Loff[64];
    __shared__ float Law[128];
    __shared__ float Lref[2];

    if (tid < 64) {
        const int hh = tid >> 3, r = tid & 7;
        Loff[tid] = offb[(int64_t)bt * 256 + hh * 32 + l * 8 + r];
    }
    if (tid < 128) Law[tid] = awl[(int64_t)bt * 128 + tid];
    if (tid < 2)   Lref[tid] = refp[(int64_t)bt * 8 + l * 2 + tid];
    __syncthreads();

    float m = -1e30f;
#pragma unroll
    for (int i = 0; i < 16; ++i) m = fmaxf(m, Law[h * 16 + i]);
    float s = 0.f;
#pragma unroll
    for (int i = 0; i < 16; ++i) s += __expf(Law[h * 16 + i] - m);
    const float invs = 1.f / s;

    const float fx = Lref[0], fy = Lref[1];
    const int HW = Hl * Wl;

    float acc = 0.f;
#pragma unroll
    for (int p = 0; p < P_; ++p) {
        const float ox = Loff[h * 8 + p * 2 + 0];
        const float oy = Loff[h * 8 + p * 2 + 1];
        const float x = (fx + ox / (float)Wl) * (float)Wl - 0.5f;
        const float y = (fy + oy / (float)Hl) * (float)Hl - 0.5f;
        const float x0f = floorf(x), y0f = floorf(y);
        const int x0 = (int)x0f, y0 = (int)y0f;
        const float lw = x - x0f, lh = y - y0f;
        const float w00 = (1.f - lw) * (1.f - lh), w10 = lw * (1.f - lh);
        const float w01 = (1.f - lw) * lh,         w11 = lw * lh;
        const float aww = __expf(Law[h * 16 + l * 4 + p] - m) * invs;

        float sv = 0.f;
        int ix, iy; float w;
#pragma unroll
        for (int cidx = 0; cidx < 4; ++cidx) {
            if (cidx == 0) { ix = x0;     iy = y0;     w = w00; }
            if (cidx == 1) { ix = x0 + 1; iy = y0;     w = w10; }
            if (cidx == 2) { ix = x0;     iy = y0 + 1; w = w01; }
            if (cidx == 3) { ix = x0 + 1; iy = y0 + 1; w = w11; }
            if (ix >= 0 && ix < Wl && iy >= 0 && iy < Hl) {
                const int64_t vi = (((int64_t)b * HW + iy * Wl + ix) * NH_ + h) * DH_ + d;
                sv += w * b2f(value_l[vi]);
            }
        }
        acc += sv * aww;
    }
    const int64_t oi = (int64_t)bt * 256 + tid;
    if (INIT) samp[oi] = f2b(acc);
    else      samp[oi] = f2b(b2f(samp[oi]) + acc);
}

// ---------------------------------------------------------------------------
extern "C" void kernel_launch(void* const* d_in, const int* in_sizes, int n_in,
                              void* d_out, int out_size, void* d_ws, size_t ws_size,
                              hipStream_t stream)
{
    const float* query = (const float*)d_in[0];
    const float* key   = (const float*)d_in[1];
    const float* refp  = (const float*)d_in[4];
    const float* W_in  = (const float*)d_in[5];
    const float* b_in  = (const float*)d_in[6];
    const float* W_out = (const float*)d_in[7];
    const float* b_out = (const float*)d_in[8];
    const float* W_off = (const float*)d_in[9];
    const float* b_off = (const float*)d_in[10];
    const float* W_aw  = (const float*)d_in[11];
    const float* b_aw  = (const float*)d_in[12];
    const float* W_v   = (const float*)d_in[13];
    const float* b_v   = (const float*)d_in[14];
    const float* W_o   = (const float*)d_in[15];
    const float* b_o   = (const float*)d_in[16];
    const float* W1    = (const float*)d_in[17];
    const float* b1    = (const float*)d_in[18];
    const float* W2    = (const float*)d_in[19];
    const float* b2    = (const float*)d_in[20];
    const float* g1    = (const float*)d_in[21];
    const float* be1   = (const float*)d_in[22];
    const float* g2    = (const float*)d_in[23];
    const float* be2   = (const float*)d_in[24];
    const float* g3    = (const float*)d_in[25];
    const float* be3   = (const float*)d_in[26];

    // Workspace plan — total 84,377,600 B (< 88.1 MB known-good):
    //  X [62,259,200]: attention phase {qkv 22.1M | S 26.7M | queryT 3.7M | VT 3.8M | attno 3.7M}
    //                  -> per-level valL (<=62.3M) -> ffh 29.5M
    //  Y [7,372,800]:  proj -> offb -> proj2 -> ffo
    //  Z1[7,372,800]:  q1
    //  W2[3,686,400]:  q1b -> samp
    //  W4[3,686,400]:  awl -> q2nb
    char* X  = (char*)d_ws;
    char* Yb = X + 62259200;
    char* Z1 = Yb + 7372800;
    char* Wa = Z1 + 7372800;
    char* Wb = Wa + 3686400;

    float* qkv    = (float*)X;
    short* S      = (short*)(X + 22118400);
    short* queryT = (short*)(X + 48844800);
    short* VT     = (short*)(X + 52531200);
    short* attno  = (short*)(X + 56332288);
    short* valL   = (short*)X;
    short* ffh    = (short*)X;
    float* proj   = (float*)Yb;
    float* offb   = (float*)Yb;
    float* proj2  = (float*)Yb;
    float* ffo    = (float*)Yb;
    float* q1     = (float*)Z1;
    short* q1b    = (short*)Wa;
    short* samp   = (short*)Wa;
    float* awl    = (float*)Wb;
    short* q2nb   = (short*)Wb;

    const int HL[4] = {100, 50, 25, 13};
    const int WL[4] = {152, 76, 38, 19};
    const int ST[4] = {0, 15200, 19000, 19950};

    // 1. queryT = bf16 transpose of query
    transpose_kernel<<<dim3(29, 8, B_), 256, 0, stream>>>(query, queryT, PQ_, PQ_,
                                                          (int64_t)C_ * PQ_, (int64_t)PQ_ * C_);
    // 2. qkv = queryT @ W_in^T + b_in  (fp32 out)
    mfma_launch<false, true, true, false>(queryT, W_in, b_in, qkv, 1, 1, B_ * PQ_, 768, 256,
                                          256, 256, 768, 0, 0, 0, 0, 0, 0, 1.f, stream);
    // 3. VT: transposed V with zero pad to 928
    vt_kernel<<<dim3(29, 64), 256, 0, stream>>>(qkv, VT);
    // 4. attention in chunks of 2 batches (16 bh)
    const float iscale = 0.17677669529663687f; // 1/sqrt(32)
    for (int cchunk = 0; cchunk < 4; ++cchunk) {
        const int b0 = cchunk * 2;
        const float* Aq = qkv + (int64_t)b0 * 900 * 768;
        const float* Wk = qkv + (int64_t)b0 * 900 * 768 + 256;
        // S = scale * Q K^T   (bf16 out, ld 928)
        mfma_launch<true, true, false, false>(Aq, Wk, nullptr, S, 16, 8, 900, 900, 32,
                                              768, 768, SLD,
                                              (int64_t)900 * 768, 32, (int64_t)900 * 768, 32,
                                              (int64_t)8 * 900 * SLD, (int64_t)900 * SLD,
                                              iscale, stream);
        softmax_kernel<<<16 * 900, 256, 0, stream>>>(S);
        // attno = P V   (bf16 out into (B*PQ,256) at head col offset)
        mfma_launch<false, false, false, false>(S, VT + (int64_t)b0 * 8 * 32 * SLD, nullptr,
                                                attno + (int64_t)b0 * 900 * 256, 16, 8,
                                                900, 32, SLD, SLD, SLD, 256,
                                                (int64_t)8 * 900 * SLD, (int64_t)900 * SLD,
                                                (int64_t)8 * 32 * SLD, (int64_t)32 * SLD,
                                                (int64_t)900 * 256, 32, 1.f, stream);
    }
    // 5. proj = attno @ W_out^T + b_out
    mfma_launch<false, true, true, false>(attno, W_out, b_out, proj, 1, 1, B_ * PQ_, 256, 256,
                                          256, 256, 256, 0, 0, 0, 0, 0, 0, 1.f, stream);
    // 6. q1 = LN(x + proj)  (fp32 + bf16)
    ln_kernel<0><<<B_ * PQ_, 256, 0, stream>>>(proj, query, g1, be1, q1, q1b);
    // 7. offsets / attention-weight logits
    mfma_launch<false, true, true, false>(q1b, W_off, b_off, offb, 1, 1, B_ * PQ_, 256, 256,
                                          256, 256, 256, 0, 0, 0, 0, 0, 0, 1.f, stream);
    mfma_launch<false, true, true, false>(q1b, W_aw, b_aw, awl, 1, 1, B_ * PQ_, 128, 256,
                                          256, 256, 128, 0, 0, 0, 0, 0, 0, 1.f, stream);
    // 8. per level: transpose key slice -> valL; in-place value GEMM; deform accumulate
    for (int l = 0; l < L_; ++l) {
        const int HW = HL[l] * WL[l];
        transpose_kernel<<<dim3((HW + 31) / 32, 8, B_), 256, 0, stream>>>(
            key + ST[l], valL, HW, PK_, (int64_t)C_ * PK_, (int64_t)HW * 256);
        mfma_launch<false, true, false, false>(valL, W_v, b_v, valL, 8, 1, HW, 256, 256,
                                               256, 256, 256,
                                               (int64_t)HW * 256, 0, 0, 0,
                                               (int64_t)HW * 256, 0, 1.f, stream);
        if (l == 0)
            deform_level_kernel<true ><<<B_ * PQ_, 256, 0, stream>>>(offb, awl, refp, valL, samp, l, HL[l], WL[l]);
        else
            deform_level_kernel<false><<<B_ * PQ_, 256, 0, stream>>>(offb, awl, refp, valL, samp, l, HL[l], WL[l]);
    }
    // 9. proj2 = samp @ W_o^T + b_o
    mfma_launch<false, true, true, false>(samp, W_o, b_o, proj2, 1, 1, B_ * PQ_, 256, 256,
                                          256, 256, 256, 0, 0, 0, 0, 0, 0, 1.f, stream);
    // 10. q2nb = LN(q1 + proj2)  (bf16)
    ln_kernel<1><<<B_ * PQ_, 256, 0, stream>>>(proj2, q1, g2, be2, nullptr, q2nb);
    // 11. ffh = relu(q2nb @ W1^T + b1)  (bf16)
    mfma_launch<false, true, false, true>(q2nb, W1, b1, ffh, 1, 1, B_ * PQ_, FF_, 256,
                                          256, 256, FF_, 0, 0, 0, 0, 0, 0, 1.f, stream);
    // 12. ffo = ffh @ W2^T + b2
    mfma_launch<false, true, true, false>(ffh, W2, b2, ffo, 1, 1, B_ * PQ_, 256, FF_,
                                          FF_, FF_, 256, 0, 0, 0, 0, 0, 0, 1.f, stream);
    // 13. d_out = LN(q2nb + ffo), transposed to (B,C,PQ)
    ln_kernel<2><<<B_ * PQ_, 256, 0, stream>>>(ffo, q2nb, g3, be3, (float*)d_out, nullptr);

    (void)in_sizes; (void)n_in; (void)out_size; (void)ws_size;
}

// Round 4
// 1023.549 us; speedup vs baseline: 2.6013x; 1.6843x over previous
//
#include <hip/hip_runtime.h>
#include <hip/hip_bf16.h>
#include <stdint.h>

typedef __hip_bfloat16 bf16;
typedef short bf16x8 __attribute__((ext_vector_type(8)));
typedef short s4v    __attribute__((ext_vector_type(4)));
typedef float f32x4  __attribute__((ext_vector_type(4)));

constexpr int B_  = 8;
constexpr int PQ_ = 900;
constexpr int C_  = 256;
constexpr int NH_ = 8;
constexpr int L_  = 4;
constexpr int P_  = 4;
constexpr int FF_ = 2048;
constexpr int DH_ = 32;
constexpr int PK_ = 20197;
constexpr int SLD = 928;    // padded score row length (29*32)

__device__ __forceinline__ short f2b(float f) {
    __hip_bfloat16 h = __float2bfloat16(f);
    union { __hip_bfloat16 h; short s; } u; u.h = h; return u.s;
}
__device__ __forceinline__ float b2f(short s) {
    union { short s; __hip_bfloat16 h; } u; u.s = s; return __bfloat162float(u.h);
}

// ---------------------------------------------------------------------------
// Generalized batched MFMA GEMM, latency-optimized for skinny shapes.
// C[batch][m][n] = act( scale * sum_k A[batch][m][k] * W[batch][n][k] + bias[n] )
// Tile: BM=64, BN=64*NF, BK=64. 256 thr = 4 waves; wave w owns cols
// [w*16*NF, (w+1)*16*NF). DBUF: register-prefetch double-buffered LDS,
// ONE barrier per K-iter. NF=4 (wide) is single-buffered (LDS 46 KB < 64 KB)
// and used only where grid.x must be 1 (in-place value GEMM).
// LDS rows = 72 shorts (144 B, 16B-aligned): ds_read_b128 fragment reads give
// 8 lanes per 4-bank group — even, no throughput-relevant conflicts.
// All K values must be multiples of 8 (guards are 8-granular): 32/256/928/2048 ok.
// ---------------------------------------------------------------------------
template <int NF, bool DBUF, bool AF32, bool WF32, bool CF32, bool RELU>
__launch_bounds__(256)
__global__ void mfma_gemm(const void* __restrict__ Ap, const void* __restrict__ Wp,
                          const float* __restrict__ bias, void* __restrict__ Cp,
                          int Mb, int N, int K, int tilesM,
                          int ldA, int ldW, int ldC, int nbI,
                          int64_t sAo, int64_t sAi, int64_t sWo, int64_t sWi,
                          int64_t sCo, int64_t sCi, float scale)
{
    constexpr int BN  = 64 * NF;
    constexpr int LDR = 72;
    constexpr int NB  = DBUF ? 2 : 1;
    __shared__ short As[NB * 64 * LDR];
    __shared__ short Ws[NB * BN * LDR];

    const int tid   = threadIdx.x;
    const int batch = blockIdx.y / tilesM;
    const int m0    = (blockIdx.y % tilesM) * 64;
    const int n0    = blockIdx.x * BN;
    const int outer = batch / nbI, inner = batch % nbI;
    const int64_t offA = (int64_t)outer * sAo + (int64_t)inner * sAi;
    const int64_t offW = (int64_t)outer * sWo + (int64_t)inner * sWi;
    const int64_t offC = (int64_t)outer * sCo + (int64_t)inner * sCi;

    const int w = tid >> 6, lane = tid & 63;
    const int quad = lane >> 4, lrow = lane & 15;
    const int colbase = n0 + w * 16 * NF;

    const int sm  = tid >> 2;          // staging row within 64-row group
    const int skb = (tid & 3) * 16;    // staging k base

    const int T = (K + 63) / 64;

    bf16x8 areg[2];
    bf16x8 wreg[2 * NF];

    auto stageA = [&](int t) {
        const int k0 = t * 64;
        const int gm = m0 + sm;
#pragma unroll
        for (int c = 0; c < 2; ++c) {
            const int k = k0 + skb + c * 8;
            bf16x8 pk = {0, 0, 0, 0, 0, 0, 0, 0};
            if (gm < Mb && k + 8 <= K) {
                if (AF32) {
                    const float* s = (const float*)Ap + offA + (int64_t)gm * ldA + k;
                    float4 u0 = *(const float4*)s;
                    float4 u1 = *(const float4*)(s + 4);
                    pk = (bf16x8){f2b(u0.x), f2b(u0.y), f2b(u0.z), f2b(u0.w),
                                  f2b(u1.x), f2b(u1.y), f2b(u1.z), f2b(u1.w)};
                } else {
                    pk = *(const bf16x8*)((const short*)Ap + offA + (int64_t)gm * ldA + k);
                }
            }
            areg[c] = pk;
        }
    };
    auto stageW = [&](int t) {
        const int k0 = t * 64;
#pragma unroll
        for (int j = 0; j < NF; ++j) {
            const int gn = n0 + j * 64 + sm;
#pragma unroll
            for (int c = 0; c < 2; ++c) {
                const int k = k0 + skb + c * 8;
                bf16x8 pk = {0, 0, 0, 0, 0, 0, 0, 0};
                if (gn < N && k + 8 <= K) {
                    if (WF32) {
                        const float* s = (const float*)Wp + offW + (int64_t)gn * ldW + k;
                        float4 u0 = *(const float4*)s;
                        float4 u1 = *(const float4*)(s + 4);
                        pk = (bf16x8){f2b(u0.x), f2b(u0.y), f2b(u0.z), f2b(u0.w),
                                      f2b(u1.x), f2b(u1.y), f2b(u1.z), f2b(u1.w)};
                    } else {
                        pk = *(const bf16x8*)((const short*)Wp + offW + (int64_t)gn * ldW + k);
                    }
                }
                wreg[j * 2 + c] = pk;
            }
        }
    };
    auto writeLDS = [&](int buf) {
#pragma unroll
        for (int c = 0; c < 2; ++c)
            *(bf16x8*)&As[(buf * 64 + sm) * LDR + skb + c * 8] = areg[c];
#pragma unroll
        for (int j = 0; j < NF; ++j)
#pragma unroll
            for (int c = 0; c < 2; ++c)
                *(bf16x8*)&Ws[(buf * BN + j * 64 + sm) * LDR + skb + c * 8] = wreg[j * 2 + c];
    };

    f32x4 acc[4][NF];
#pragma unroll
    for (int i = 0; i < 4; ++i)
#pragma unroll
        for (int j = 0; j < NF; ++j) acc[i][j] = (f32x4){0.f, 0.f, 0.f, 0.f};

    auto compute = [&](int buf) {
        bf16x8 a[4][2], bb[NF][2];
#pragma unroll
        for (int kh = 0; kh < 2; ++kh) {
#pragma unroll
            for (int mf = 0; mf < 4; ++mf)
                a[mf][kh] = *(const bf16x8*)&As[(buf * 64 + mf * 16 + lrow) * LDR + kh * 32 + quad * 8];
#pragma unroll
            for (int nf = 0; nf < NF; ++nf)
                bb[nf][kh] = *(const bf16x8*)&Ws[(buf * BN + w * 16 * NF + nf * 16 + lrow) * LDR + kh * 32 + quad * 8];
        }
#pragma unroll
        for (int kh = 0; kh < 2; ++kh)
#pragma unroll
            for (int mf = 0; mf < 4; ++mf)
#pragma unroll
                for (int nf = 0; nf < NF; ++nf)
                    acc[mf][nf] = __builtin_amdgcn_mfma_f32_16x16x32_bf16(a[mf][kh], bb[nf][kh], acc[mf][nf], 0, 0, 0);
    };

    if (DBUF) {
        stageA(0); stageW(0); writeLDS(0);
        __syncthreads();
        for (int t = 0; t < T; ++t) {
            const int cur = t & 1;
            if (t + 1 < T) { stageA(t + 1); stageW(t + 1); }
            compute(cur);
            if (t + 1 < T) {
                writeLDS(cur ^ 1);
                __syncthreads();
            }
        }
    } else {
        for (int t = 0; t < T; ++t) {
            stageA(t); stageW(t);
            if (t > 0) __syncthreads();
            writeLDS(0);
            __syncthreads();
            compute(0);
        }
    }

    // epilogue
#pragma unroll
    for (int nf = 0; nf < NF; ++nf) {
        const int col = colbase + nf * 16 + lrow;
        if (col >= N) continue;
        const float bia = bias ? bias[col] : 0.f;
#pragma unroll
        for (int mf = 0; mf < 4; ++mf) {
            const int row0 = m0 + mf * 16 + quad * 4;
#pragma unroll
            for (int r = 0; r < 4; ++r) {
                const int rr = row0 + r;
                if (rr < Mb) {
                    float v = acc[mf][nf][r] * scale + bia;
                    if (RELU) v = fmaxf(v, 0.f);
                    const int64_t idx = offC + (int64_t)rr * ldC + col;
                    if (CF32) ((float*)Cp)[idx] = v;
                    else      ((short*)Cp)[idx] = f2b(v);
                }
            }
        }
    }
}

template <int NF, bool DBUF, bool AF32, bool WF32, bool CF32, bool RELU>
static void mfma_launch(const void* A, const void* W, const float* bias, void* Cp,
                        int nb, int nbI, int Mb, int N, int K,
                        int ldA, int ldW, int ldC,
                        int64_t sAo, int64_t sAi, int64_t sWo, int64_t sWi,
                        int64_t sCo, int64_t sCi, float scale, hipStream_t stream)
{
    int tilesM = (Mb + 63) / 64;
    dim3 grid((N + 64 * NF - 1) / (64 * NF), nb * tilesM);
    mfma_gemm<NF, DBUF, AF32, WF32, CF32, RELU><<<grid, 256, 0, stream>>>(
        A, W, bias, Cp, Mb, N, K, tilesM, ldA, ldW, ldC, nbI,
        sAo, sAi, sWo, sWi, sCo, sCi, scale);
}

// ---------------------------------------------------------------------------
// 32x32 tile transpose: dst[b][s][c] (bf16, row=256) = src[b*sbs + (c0+c)*ldS + s]
// ---------------------------------------------------------------------------
__launch_bounds__(256)
__global__ void transpose_kernel(const float* __restrict__ src, short* __restrict__ dst,
                                 int Scount, int ldS, int64_t sbs, int64_t dbs)
{
    const int tid = threadIdx.x;
    const int b = blockIdx.z;
    const int s0 = blockIdx.x * 32, c0 = blockIdx.y * 32;
    __shared__ float t[32][33];
    {
        const int c_l = tid >> 3, sq = (tid & 7) * 4;
        const int64_t base = (int64_t)b * sbs + (int64_t)(c0 + c_l) * ldS;
#pragma unroll
        for (int i = 0; i < 4; ++i) {
            const int s = s0 + sq + i;
            t[c_l][sq + i] = (s < Scount) ? src[base + s] : 0.f;
        }
    }
    __syncthreads();
    {
        const int s_l = tid >> 3, cq = (tid & 7) * 4;
        const int s = s0 + s_l;
        if (s < Scount) {
            s4v pk = {f2b(t[cq + 0][s_l]), f2b(t[cq + 1][s_l]),
                      f2b(t[cq + 2][s_l]), f2b(t[cq + 3][s_l])};
            *(s4v*)&dst[(int64_t)b * dbs + (int64_t)s * 256 + c0 + cq] = pk;
        }
    }
}

// ---------------------------------------------------------------------------
// VT[bh][d][s] (bf16, ld=928, s>=900 zero) = qkv[(b*900+s)*768 + 512 + h*32 + d]
// ---------------------------------------------------------------------------
__launch_bounds__(256)
__global__ void vt_kernel(const float* __restrict__ qkv, short* __restrict__ VT)
{
    const int tid = threadIdx.x;
    const int bh = blockIdx.y, b = bh >> 3, h = bh & 7;
    const int s0 = blockIdx.x * 32;
    __shared__ float t[32][33];
    {
        const int s_l = tid >> 3, dq = (tid & 7) * 4;
        const int s = s0 + s_l;
        float x0 = 0.f, x1 = 0.f, x2 = 0.f, x3 = 0.f;
        if (s < 900) {
            float4 u = *(const float4*)&qkv[((int64_t)(b * 900 + s)) * 768 + 512 + h * 32 + dq];
            x0 = u.x; x1 = u.y; x2 = u.z; x3 = u.w;
        }
        t[s_l][dq + 0] = x0; t[s_l][dq + 1] = x1; t[s_l][dq + 2] = x2; t[s_l][dq + 3] = x3;
    }
    __syncthreads();
    {
        const int d = tid >> 3, sq = (tid & 7) * 4;
        s4v pk = {f2b(t[sq + 0][d]), f2b(t[sq + 1][d]), f2b(t[sq + 2][d]), f2b(t[sq + 3][d])};
        *(s4v*)&VT[(int64_t)bh * 32 * SLD + (int64_t)d * SLD + s0 + sq] = pk;
    }
}

// ---------------------------------------------------------------------------
// In-place row softmax over bf16 score rows (900 valid of 928; pads = 0)
// ---------------------------------------------------------------------------
__launch_bounds__(256)
__global__ void softmax_kernel(short* __restrict__ S)
{
    const int tid = threadIdx.x;
    const int64_t base = (int64_t)blockIdx.x * SLD;
    float v[4];
    int idx[4] = {tid, tid + 256, tid + 512, tid + 768};
    float mx = -1e30f;
#pragma unroll
    for (int i = 0; i < 4; ++i) {
        if (idx[i] < 900) { v[i] = b2f(S[base + idx[i]]); mx = fmaxf(mx, v[i]); }
        else v[i] = -1e30f;
    }
    __shared__ float red[256];
    red[tid] = mx; __syncthreads();
    for (int st = 128; st > 0; st >>= 1) {
        if (tid < st) red[tid] = fmaxf(red[tid], red[tid + st]);
        __syncthreads();
    }
    const float m = red[0];
    __syncthreads();
    float sm = 0.f;
#pragma unroll
    for (int i = 0; i < 4; ++i)
        if (idx[i] < 900) { v[i] = __expf(v[i] - m); sm += v[i]; }
    red[tid] = sm; __syncthreads();
    for (int st = 128; st > 0; st >>= 1) {
        if (tid < st) red[tid] += red[tid + st];
        __syncthreads();
    }
    const float inv = 1.f / red[0];
#pragma unroll
    for (int i = 0; i < 4; ++i)
        if (idx[i] < 900) S[base + idx[i]] = f2b(v[i] * inv);
    if (tid < SLD - 900) S[base + 900 + tid] = 0;
}

// ---------------------------------------------------------------------------
// Residual + LayerNorm over C=256, one block per (b,t).
// MODE 0: res = query (B,C,PQ) fp32 transposed-read; out q1 fp32 + q1b bf16
// MODE 1: res = q1 fp32 (BT,C);                      out q2nb bf16 only
// MODE 2: res = q2nb bf16 (BT,C);                    out d_out fp32 (B,C,PQ)
// ---------------------------------------------------------------------------
template <int MODE>
__launch_bounds__(256)
__global__ void ln_kernel(const float* __restrict__ y, const void* __restrict__ res,
                          const float* __restrict__ g, const float* __restrict__ be,
                          float* __restrict__ out_f, short* __restrict__ out_b)
{
    const int bt = blockIdx.x;
    const int b = bt / PQ_, t = bt % PQ_;
    const int c = threadIdx.x;

    float r;
    if (MODE == 0)      r = ((const float*)res)[((int64_t)b * C_ + c) * PQ_ + t];
    else if (MODE == 1) r = ((const float*)res)[(int64_t)bt * C_ + c];
    else                r = b2f(((const short*)res)[(int64_t)bt * C_ + c]);
    const float v = r + y[(int64_t)bt * C_ + c];

    __shared__ float s1[256], s2[256];
    s1[c] = v; s2[c] = v * v;
    __syncthreads();
    for (int st = 128; st > 0; st >>= 1) {
        if (c < st) { s1[c] += s1[c + st]; s2[c] += s2[c + st]; }
        __syncthreads();
    }
    const float mean = s1[0] * (1.f / C_);
    const float var  = s2[0] * (1.f / C_) - mean * mean;
    const float o = (v - mean) * rsqrtf(var + 1e-5f) * g[c] + be[c];

    if (MODE == 0) { out_f[(int64_t)bt * C_ + c] = o; out_b[(int64_t)bt * C_ + c] = f2b(o); }
    else if (MODE == 1) out_b[(int64_t)bt * C_ + c] = f2b(o);
    else out_f[((int64_t)b * C_ + c) * PQ_ + t] = o;
}

// ---------------------------------------------------------------------------
// MS-deformable sampling for one level, accumulating into samp (bf16).
// value_l: (B, Hl*Wl, NH, DH) bf16. One block per (b,q); thread=(h=tid>>5,d=tid&31).
// ---------------------------------------------------------------------------
template <bool INIT>
__launch_bounds__(256)
__global__ void deform_level_kernel(const float* __restrict__ offb, const float* __restrict__ awl,
                                    const float* __restrict__ refp, const short* __restrict__ value_l,
                                    short* __restrict__ samp, int l, int Hl, int Wl)
{
    const int bt = blockIdx.x;
    const int b = bt / PQ_;
    const int tid = threadIdx.x;
    const int h = tid >> 5, d = tid & 31;

    __shared__ float Loff[64];
    __shared__ float Law[128];
    __shared__ float Lref[2];

    if (tid < 64) {
        const int hh = tid >> 3, r = tid & 7;
        Loff[tid] = offb[(int64_t)bt * 256 + hh * 32 + l * 8 + r];
    }
    if (tid < 128) Law[tid] = awl[(int64_t)bt * 128 + tid];
    if (tid < 2)   Lref[tid] = refp[(int64_t)bt * 8 + l * 2 + tid];
    __syncthreads();

    float m = -1e30f;
#pragma unroll
    for (int i = 0; i < 16; ++i) m = fmaxf(m, Law[h * 16 + i]);
    float s = 0.f;
#pragma unroll
    for (int i = 0; i < 16; ++i) s += __expf(Law[h * 16 + i] - m);
    const float invs = 1.f / s;

    const float fx = Lref[0], fy = Lref[1];
    const int HW = Hl * Wl;

    float acc = 0.f;
#pragma unroll
    for (int p = 0; p < P_; ++p) {
        const float ox = Loff[h * 8 + p * 2 + 0];
        const float oy = Loff[h * 8 + p * 2 + 1];
        const float x = (fx + ox / (float)Wl) * (float)Wl - 0.5f;
        const float y = (fy + oy / (float)Hl) * (float)Hl - 0.5f;
        const float x0f = floorf(x), y0f = floorf(y);
        const int x0 = (int)x0f, y0 = (int)y0f;
        const float lw = x - x0f, lh = y - y0f;
        const float w00 = (1.f - lw) * (1.f - lh), w10 = lw * (1.f - lh);
        const float w01 = (1.f - lw) * lh,         w11 = lw * lh;
        const float aww = __expf(Law[h * 16 + l * 4 + p] - m) * invs;

        float sv = 0.f;
        int ix, iy; float w;
#pragma unroll
        for (int cidx = 0; cidx < 4; ++cidx) {
            if (cidx == 0) { ix = x0;     iy = y0;     w = w00; }
            if (cidx == 1) { ix = x0 + 1; iy = y0;     w = w10; }
            if (cidx == 2) { ix = x0;     iy = y0 + 1; w = w01; }
            if (cidx == 3) { ix = x0 + 1; iy = y0 + 1; w = w11; }
            if (ix >= 0 && ix < Wl && iy >= 0 && iy < Hl) {
                const int64_t vi = (((int64_t)b * HW + iy * Wl + ix) * NH_ + h) * DH_ + d;
                sv += w * b2f(value_l[vi]);
            }
        }
        acc += sv * aww;
    }
    const int64_t oi = (int64_t)bt * 256 + tid;
    if (INIT) samp[oi] = f2b(acc);
    else      samp[oi] = f2b(b2f(samp[oi]) + acc);
}

// ---------------------------------------------------------------------------
extern "C" void kernel_launch(void* const* d_in, const int* in_sizes, int n_in,
                              void* d_out, int out_size, void* d_ws, size_t ws_size,
                              hipStream_t stream)
{
    const float* query = (const float*)d_in[0];
    const float* key   = (const float*)d_in[1];
    const float* refp  = (const float*)d_in[4];
    const float* W_in  = (const float*)d_in[5];
    const float* b_in  = (const float*)d_in[6];
    const float* W_out = (const float*)d_in[7];
    const float* b_out = (const float*)d_in[8];
    const float* W_off = (const float*)d_in[9];
    const float* b_off = (const float*)d_in[10];
    const float* W_aw  = (const float*)d_in[11];
    const float* b_aw  = (const float*)d_in[12];
    const float* W_v   = (const float*)d_in[13];
    const float* b_v   = (const float*)d_in[14];
    const float* W_o   = (const float*)d_in[15];
    const float* b_o   = (const float*)d_in[16];
    const float* W1    = (const float*)d_in[17];
    const float* b1    = (const float*)d_in[18];
    const float* W2    = (const float*)d_in[19];
    const float* b2    = (const float*)d_in[20];
    const float* g1    = (const float*)d_in[21];
    const float* be1   = (const float*)d_in[22];
    const float* g2    = (const float*)d_in[23];
    const float* be2   = (const float*)d_in[24];
    const float* g3    = (const float*)d_in[25];
    const float* be3   = (const float*)d_in[26];

    // Workspace plan — total 84,377,600 B (known-good from round 3):
    //  X [62,259,200]: {qkv | S | queryT | VT | attno} -> per-level valL -> ffh
    //  Y: proj -> offb -> proj2 -> ffo ; Z1: q1 ; Wa: q1b -> samp ; Wb: awl -> q2nb
    char* X  = (char*)d_ws;
    char* Yb = X + 62259200;
    char* Z1 = Yb + 7372800;
    char* Wa = Z1 + 7372800;
    char* Wb = Wa + 3686400;

    float* qkv    = (float*)X;
    short* S      = (short*)(X + 22118400);
    short* queryT = (short*)(X + 48844800);
    short* VT     = (short*)(X + 52531200);
    short* attno  = (short*)(X + 56332288);
    short* valL   = (short*)X;
    short* ffh    = (short*)X;
    float* proj   = (float*)Yb;
    float* offb   = (float*)Yb;
    float* proj2  = (float*)Yb;
    float* ffo    = (float*)Yb;
    float* q1     = (float*)Z1;
    short* q1b    = (short*)Wa;
    short* samp   = (short*)Wa;
    float* awl    = (float*)Wb;
    short* q2nb   = (short*)Wb;

    const int HL[4] = {100, 50, 25, 13};
    const int WL[4] = {152, 76, 38, 19};
    const int ST[4] = {0, 15200, 19000, 19950};

    // 1. queryT = bf16 transpose of query
    transpose_kernel<<<dim3(29, 8, B_), 256, 0, stream>>>(query, queryT, PQ_, PQ_,
                                                          (int64_t)C_ * PQ_, (int64_t)PQ_ * C_);
    // 2. qkv = queryT @ W_in^T + b_in  (fp32 out)
    mfma_launch<1, true, false, true, true, false>(queryT, W_in, b_in, qkv, 1, 1, B_ * PQ_, 768, 256,
                                                   256, 256, 768, 0, 0, 0, 0, 0, 0, 1.f, stream);
    // 3. VT: transposed V with zero pad to 928
    vt_kernel<<<dim3(29, 64), 256, 0, stream>>>(qkv, VT);
    // 4. attention in chunks of 2 batches (16 bh)
    const float iscale = 0.17677669529663687f; // 1/sqrt(32)
    for (int cchunk = 0; cchunk < 4; ++cchunk) {
        const int b0 = cchunk * 2;
        const float* Aq = qkv + (int64_t)b0 * 900 * 768;
        const float* Wk = qkv + (int64_t)b0 * 900 * 768 + 256;
        // S = scale * Q K^T   (bf16 out, ld 928)
        mfma_launch<1, true, true, true, false, false>(Aq, Wk, nullptr, S, 16, 8, 900, 900, 32,
                                                       768, 768, SLD,
                                                       (int64_t)900 * 768, 32, (int64_t)900 * 768, 32,
                                                       (int64_t)8 * 900 * SLD, (int64_t)900 * SLD,
                                                       iscale, stream);
        softmax_kernel<<<16 * 900, 256, 0, stream>>>(S);
        // attno = P V   (bf16 out into (B*PQ,256) at head col offset)
        mfma_launch<1, true, false, false, false, false>(S, VT + (int64_t)b0 * 8 * 32 * SLD, nullptr,
                                                         attno + (int64_t)b0 * 900 * 256, 16, 8,
                                                         900, 32, SLD, SLD, SLD, 256,
                                                         (int64_t)8 * 900 * SLD, (int64_t)900 * SLD,
                                                         (int64_t)8 * 32 * SLD, (int64_t)32 * SLD,
                                                         (int64_t)900 * 256, 32, 1.f, stream);
    }
    // 5. proj = attno @ W_out^T + b_out
    mfma_launch<1, true, false, true, true, false>(attno, W_out, b_out, proj, 1, 1, B_ * PQ_, 256, 256,
                                                   256, 256, 256, 0, 0, 0, 0, 0, 0, 1.f, stream);
    // 6. q1 = LN(x + proj)  (fp32 + bf16)
    ln_kernel<0><<<B_ * PQ_, 256, 0, stream>>>(proj, query, g1, be1, q1, q1b);
    // 7. offsets / attention-weight logits
    mfma_launch<1, true, false, true, true, false>(q1b, W_off, b_off, offb, 1, 1, B_ * PQ_, 256, 256,
                                                   256, 256, 256, 0, 0, 0, 0, 0, 0, 1.f, stream);
    mfma_launch<1, true, false, true, true, false>(q1b, W_aw, b_aw, awl, 1, 1, B_ * PQ_, 128, 256,
                                                   256, 256, 128, 0, 0, 0, 0, 0, 0, 1.f, stream);
    // 8. per level: transpose key slice -> valL; in-place value GEMM (wide: grid.x=1
    //    required for in-place safety); deform accumulate
    for (int l = 0; l < L_; ++l) {
        const int HW = HL[l] * WL[l];
        transpose_kernel<<<dim3((HW + 31) / 32, 8, B_), 256, 0, stream>>>(
            key + ST[l], valL, HW, PK_, (int64_t)C_ * PK_, (int64_t)HW * 256);
        mfma_launch<4, false, false, true, false, false>(valL, W_v, b_v, valL, 8, 1, HW, 256, 256,
                                                         256, 256, 256,
                                                         (int64_t)HW * 256, 0, 0, 0,
                                                         (int64_t)HW * 256, 0, 1.f, stream);
        if (l == 0)
            deform_level_kernel<true ><<<B_ * PQ_, 256, 0, stream>>>(offb, awl, refp, valL, samp, l, HL[l], WL[l]);
        else
            deform_level_kernel<false><<<B_ * PQ_, 256, 0, stream>>>(offb, awl, refp, valL, samp, l, HL[l], WL[l]);
    }
    // 9. proj2 = samp @ W_o^T + b_o
    mfma_launch<1, true, false, true, true, false>(samp, W_o, b_o, proj2, 1, 1, B_ * PQ_, 256, 256,
                                                   256, 256, 256, 0, 0, 0, 0, 0, 0, 1.f, stream);
    // 10. q2nb = LN(q1 + proj2)  (bf16)
    ln_kernel<1><<<B_ * PQ_, 256, 0, stream>>>(proj2, q1, g2, be2, nullptr, q2nb);
    // 11. ffh = relu(q2nb @ W1^T + b1)  (bf16)
    mfma_launch<1, true, false, true, false, true>(q2nb, W1, b1, ffh, 1, 1, B_ * PQ_, FF_, 256,
                                                   256, 256, FF_, 0, 0, 0, 0, 0, 0, 1.f, stream);
    // 12. ffo = ffh @ W2^T + b2
    mfma_launch<1, true, false, true, true, false>(ffh, W2, b2, ffo, 1, 1, B_ * PQ_, 256, FF_,
                                                   FF_, FF_, 256, 0, 0, 0, 0, 0, 0, 1.f, stream);
    // 13. d_out = LN(q2nb + ffo), transposed to (B,C,PQ)
    ln_kernel<2><<<B_ * PQ_, 256, 0, stream>>>(ffo, q2nb, g3, be3, (float*)d_out, nullptr);

    (void)in_sizes; (void)n_in; (void)out_size; (void)ws_size;
}

// Round 5
// 847.230 us; speedup vs baseline: 3.1426x; 1.2081x over previous
//
#include <hip/hip_runtime.h>
#include <hip/hip_bf16.h>
#include <stdint.h>

typedef __hip_bfloat16 bf16;
typedef short bf16x8 __attribute__((ext_vector_type(8)));
typedef short s4v    __attribute__((ext_vector_type(4)));
typedef float f32x4  __attribute__((ext_vector_type(4)));

constexpr int B_  = 8;
constexpr int PQ_ = 900;
constexpr int C_  = 256;
constexpr int NH_ = 8;
constexpr int L_  = 4;
constexpr int P_  = 4;
constexpr int FF_ = 2048;
constexpr int DH_ = 32;
constexpr int PK_ = 20197;
constexpr int VLD = 960;    // VT row length (15 s-tiles of 64, zero-padded past 900)

__device__ __forceinline__ short f2b(float f) {
    __hip_bfloat16 h = __float2bfloat16(f);
    union { __hip_bfloat16 h; short s; } u; u.h = h; return u.s;
}
__device__ __forceinline__ float b2f(short s) {
    union { short s; __hip_bfloat16 h; } u; u.s = s; return __bfloat162float(u.h);
}

// ---------------------------------------------------------------------------
// Generalized batched MFMA GEMM (round-4, known good).
// C[batch][m][n] = act( scale * sum_k A[batch][m][k] * W[batch][n][k] + bias[n] )
// BM=64, BN=64*NF, BK=64; DBUF = register-prefetch double-buffered LDS,
// one barrier per K-iter. NF=4 single-buffered, used only for in-place value GEMM.
// ---------------------------------------------------------------------------
template <int NF, bool DBUF, bool AF32, bool WF32, bool CF32, bool RELU>
__launch_bounds__(256)
__global__ void mfma_gemm(const void* __restrict__ Ap, const void* __restrict__ Wp,
                          const float* __restrict__ bias, void* __restrict__ Cp,
                          int Mb, int N, int K, int tilesM,
                          int ldA, int ldW, int ldC, int nbI,
                          int64_t sAo, int64_t sAi, int64_t sWo, int64_t sWi,
                          int64_t sCo, int64_t sCi, float scale)
{
    constexpr int BN  = 64 * NF;
    constexpr int LDR = 72;
    constexpr int NB  = DBUF ? 2 : 1;
    __shared__ short As[NB * 64 * LDR];
    __shared__ short Ws[NB * BN * LDR];

    const int tid   = threadIdx.x;
    const int batch = blockIdx.y / tilesM;
    const int m0    = (blockIdx.y % tilesM) * 64;
    const int n0    = blockIdx.x * BN;
    const int outer = batch / nbI, inner = batch % nbI;
    const int64_t offA = (int64_t)outer * sAo + (int64_t)inner * sAi;
    const int64_t offW = (int64_t)outer * sWo + (int64_t)inner * sWi;
    const int64_t offC = (int64_t)outer * sCo + (int64_t)inner * sCi;

    const int w = tid >> 6, lane = tid & 63;
    const int quad = lane >> 4, lrow = lane & 15;
    const int colbase = n0 + w * 16 * NF;

    const int sm  = tid >> 2;
    const int skb = (tid & 3) * 16;

    const int T = (K + 63) / 64;

    bf16x8 areg[2];
    bf16x8 wreg[2 * NF];

    auto stageA = [&](int t) {
        const int k0 = t * 64;
        const int gm = m0 + sm;
#pragma unroll
        for (int c = 0; c < 2; ++c) {
            const int k = k0 + skb + c * 8;
            bf16x8 pk = {0, 0, 0, 0, 0, 0, 0, 0};
            if (gm < Mb && k + 8 <= K) {
                if (AF32) {
                    const float* s = (const float*)Ap + offA + (int64_t)gm * ldA + k;
                    float4 u0 = *(const float4*)s;
                    float4 u1 = *(const float4*)(s + 4);
                    pk = (bf16x8){f2b(u0.x), f2b(u0.y), f2b(u0.z), f2b(u0.w),
                                  f2b(u1.x), f2b(u1.y), f2b(u1.z), f2b(u1.w)};
                } else {
                    pk = *(const bf16x8*)((const short*)Ap + offA + (int64_t)gm * ldA + k);
                }
            }
            areg[c] = pk;
        }
    };
    auto stageW = [&](int t) {
        const int k0 = t * 64;
#pragma unroll
        for (int j = 0; j < NF; ++j) {
            const int gn = n0 + j * 64 + sm;
#pragma unroll
            for (int c = 0; c < 2; ++c) {
                const int k = k0 + skb + c * 8;
                bf16x8 pk = {0, 0, 0, 0, 0, 0, 0, 0};
                if (gn < N && k + 8 <= K) {
                    if (WF32) {
                        const float* s = (const float*)Wp + offW + (int64_t)gn * ldW + k;
                        float4 u0 = *(const float4*)s;
                        float4 u1 = *(const float4*)(s + 4);
                        pk = (bf16x8){f2b(u0.x), f2b(u0.y), f2b(u0.z), f2b(u0.w),
                                      f2b(u1.x), f2b(u1.y), f2b(u1.z), f2b(u1.w)};
                    } else {
                        pk = *(const bf16x8*)((const short*)Wp + offW + (int64_t)gn * ldW + k);
                    }
                }
                wreg[j * 2 + c] = pk;
            }
        }
    };
    auto writeLDS = [&](int buf) {
#pragma unroll
        for (int c = 0; c < 2; ++c)
            *(bf16x8*)&As[(buf * 64 + sm) * LDR + skb + c * 8] = areg[c];
#pragma unroll
        for (int j = 0; j < NF; ++j)
#pragma unroll
            for (int c = 0; c < 2; ++c)
                *(bf16x8*)&Ws[(buf * BN + j * 64 + sm) * LDR + skb + c * 8] = wreg[j * 2 + c];
    };

    f32x4 acc[4][NF];
#pragma unroll
    for (int i = 0; i < 4; ++i)
#pragma unroll
        for (int j = 0; j < NF; ++j) acc[i][j] = (f32x4){0.f, 0.f, 0.f, 0.f};

    auto compute = [&](int buf) {
        bf16x8 a[4][2], bb[NF][2];
#pragma unroll
        for (int kh = 0; kh < 2; ++kh) {
#pragma unroll
            for (int mf = 0; mf < 4; ++mf)
                a[mf][kh] = *(const bf16x8*)&As[(buf * 64 + mf * 16 + lrow) * LDR + kh * 32 + quad * 8];
#pragma unroll
            for (int nf = 0; nf < NF; ++nf)
                bb[nf][kh] = *(const bf16x8*)&Ws[(buf * BN + w * 16 * NF + nf * 16 + lrow) * LDR + kh * 32 + quad * 8];
        }
#pragma unroll
        for (int kh = 0; kh < 2; ++kh)
#pragma unroll
            for (int mf = 0; mf < 4; ++mf)
#pragma unroll
                for (int nf = 0; nf < NF; ++nf)
                    acc[mf][nf] = __builtin_amdgcn_mfma_f32_16x16x32_bf16(a[mf][kh], bb[nf][kh], acc[mf][nf], 0, 0, 0);
    };

    if (DBUF) {
        stageA(0); stageW(0); writeLDS(0);
        __syncthreads();
        for (int t = 0; t < T; ++t) {
            const int cur = t & 1;
            if (t + 1 < T) { stageA(t + 1); stageW(t + 1); }
            compute(cur);
            if (t + 1 < T) {
                writeLDS(cur ^ 1);
                __syncthreads();
            }
        }
    } else {
        for (int t = 0; t < T; ++t) {
            stageA(t); stageW(t);
            if (t > 0) __syncthreads();
            writeLDS(0);
            __syncthreads();
            compute(0);
        }
    }

#pragma unroll
    for (int nf = 0; nf < NF; ++nf) {
        const int col = colbase + nf * 16 + lrow;
        if (col >= N) continue;
        const float bia = bias ? bias[col] : 0.f;
#pragma unroll
        for (int mf = 0; mf < 4; ++mf) {
            const int row0 = m0 + mf * 16 + quad * 4;
#pragma unroll
            for (int r = 0; r < 4; ++r) {
                const int rr = row0 + r;
                if (rr < Mb) {
                    float v = acc[mf][nf][r] * scale + bia;
                    if (RELU) v = fmaxf(v, 0.f);
                    const int64_t idx = offC + (int64_t)rr * ldC + col;
                    if (CF32) ((float*)Cp)[idx] = v;
                    else      ((short*)Cp)[idx] = f2b(v);
                }
            }
        }
    }
}

template <int NF, bool DBUF, bool AF32, bool WF32, bool CF32, bool RELU>
static void mfma_launch(const void* A, const void* W, const float* bias, void* Cp,
                        int nb, int nbI, int Mb, int N, int K,
                        int ldA, int ldW, int ldC,
                        int64_t sAo, int64_t sAi, int64_t sWo, int64_t sWi,
                        int64_t sCo, int64_t sCi, float scale, hipStream_t stream)
{
    int tilesM = (Mb + 63) / 64;
    dim3 grid((N + 64 * NF - 1) / (64 * NF), nb * tilesM);
    mfma_gemm<NF, DBUF, AF32, WF32, CF32, RELU><<<grid, 256, 0, stream>>>(
        A, W, bias, Cp, Mb, N, K, tilesM, ldA, ldW, ldC, nbI,
        sAo, sAi, sWo, sWi, sCo, sCi, scale);
}

// ---------------------------------------------------------------------------
// 32x32 tile transpose: dst[b][s][c] (bf16, row=256) = src[b*sbs + (c0+c)*ldS + s]
// ---------------------------------------------------------------------------
__launch_bounds__(256)
__global__ void transpose_kernel(const float* __restrict__ src, short* __restrict__ dst,
                                 int Scount, int ldS, int64_t sbs, int64_t dbs)
{
    const int tid = threadIdx.x;
    const int b = blockIdx.z;
    const int s0 = blockIdx.x * 32, c0 = blockIdx.y * 32;
    __shared__ float t[32][33];
    {
        const int c_l = tid >> 3, sq = (tid & 7) * 4;
        const int64_t base = (int64_t)b * sbs + (int64_t)(c0 + c_l) * ldS;
#pragma unroll
        for (int i = 0; i < 4; ++i) {
            const int s = s0 + sq + i;
            t[c_l][sq + i] = (s < Scount) ? src[base + s] : 0.f;
        }
    }
    __syncthreads();
    {
        const int s_l = tid >> 3, cq = (tid & 7) * 4;
        const int s = s0 + s_l;
        if (s < Scount) {
            s4v pk = {f2b(t[cq + 0][s_l]), f2b(t[cq + 1][s_l]),
                      f2b(t[cq + 2][s_l]), f2b(t[cq + 3][s_l])};
            *(s4v*)&dst[(int64_t)b * dbs + (int64_t)s * 256 + c0 + cq] = pk;
        }
    }
}

// ---------------------------------------------------------------------------
// VT[bh][d][s] (bf16, ld=960, s>=900 zero) from bf16 qkv (B*900, 768)
// ---------------------------------------------------------------------------
__launch_bounds__(256)
__global__ void vt_kernel(const short* __restrict__ qkv, short* __restrict__ VT)
{
    const int tid = threadIdx.x;
    const int bh = blockIdx.y, b = bh >> 3, h = bh & 7;
    const int s0 = blockIdx.x * 32;
    __shared__ short t[32][36];
    {
        const int s_l = tid >> 3, dq = (tid & 7) * 4;
        const int s = s0 + s_l;
        s4v pk = {0, 0, 0, 0};
        if (s < 900)
            pk = *(const s4v*)&qkv[((int64_t)(b * 900 + s)) * 768 + 512 + h * 32 + dq];
        *(s4v*)&t[s_l][dq] = pk;
    }
    __syncthreads();
    {
        const int d = tid >> 3, sq = (tid & 7) * 4;
        s4v pk = {t[sq + 0][d], t[sq + 1][d], t[sq + 2][d], t[sq + 3][d]};
        *(s4v*)&VT[((int64_t)bh * 32 + d) * VLD + s0 + sq] = pk;
    }
}

// ---------------------------------------------------------------------------
// Fused flash-style self-attention. grid (15 q-tiles, 64 bh), 4 waves/block,
// each wave owns 16 q-rows. QK^T: A=Q frag (m=q,k=d, K=32 exact), B=K frag
// (n=s,k=d) straight from bf16 qkv. Scores exit in C-layout (col=lane&15=s,
// row=quad*4+r=q); online softmax stats per row via shfl_xor over the 16
// lanes of a quad. P converts C-layout -> A-layout through a per-wave LDS
// tile (wave-internal DS ordering, no barrier). PV: B=VT[d][s] (ld 960,
// zero-padded so the 15th 64-wide s-tile stays in bounds).
// ---------------------------------------------------------------------------
__launch_bounds__(256)
__global__ void attn_fused(const short* __restrict__ qkv, const short* __restrict__ VT,
                           short* __restrict__ attno)
{
    __shared__ short Pl[4 * 16 * 72];
    const int tid = threadIdx.x;
    const int wv = tid >> 6, lane = tid & 63;
    const int quad = lane >> 4, lrow = lane & 15;
    const int bh = blockIdx.y, b = bh >> 3, h = bh & 7;
    const int q0 = blockIdx.x * 64 + wv * 16;
    const float iscale = 0.17677669529663687f; // 1/sqrt(32)

    bf16x8 aq = {0, 0, 0, 0, 0, 0, 0, 0};
    {
        const int q = q0 + lrow;
        if (q < 900)
            aq = *(const bf16x8*)&qkv[((int64_t)(b * 900 + q)) * 768 + h * 32 + quad * 8];
    }

    float mrow[4], lsum[4];
    f32x4 o[2] = {{0.f, 0.f, 0.f, 0.f}, {0.f, 0.f, 0.f, 0.f}};
#pragma unroll
    for (int r = 0; r < 4; ++r) { mrow[r] = -1e30f; lsum[r] = 0.f; }

    short* Pw = &Pl[wv * 16 * 72];

    for (int st = 0; st < 15; ++st) {
        const int s0 = st * 64;
        f32x4 sc[4];
#pragma unroll
        for (int nf = 0; nf < 4; ++nf) {
            const int s = s0 + nf * 16 + lrow;
            bf16x8 kb = {0, 0, 0, 0, 0, 0, 0, 0};
            if (s < 900)
                kb = *(const bf16x8*)&qkv[((int64_t)(b * 900 + s)) * 768 + 256 + h * 32 + quad * 8];
            sc[nf] = __builtin_amdgcn_mfma_f32_16x16x32_bf16(aq, kb, (f32x4){0.f, 0.f, 0.f, 0.f}, 0, 0, 0);
        }
#pragma unroll
        for (int nf = 0; nf < 4; ++nf) {
            const int s = s0 + nf * 16 + lrow;
            if (s >= 900) sc[nf] = (f32x4){-1e30f, -1e30f, -1e30f, -1e30f};
            else {
#pragma unroll
                for (int r = 0; r < 4; ++r) sc[nf][r] *= iscale;
            }
        }
        float alpha[4], ps[4][4], rsum[4];
#pragma unroll
        for (int r = 0; r < 4; ++r) {
            float tm = fmaxf(fmaxf(sc[0][r], sc[1][r]), fmaxf(sc[2][r], sc[3][r]));
#pragma unroll
            for (int off = 1; off < 16; off <<= 1)
                tm = fmaxf(tm, __shfl_xor(tm, off, 64));
            const float nm = fmaxf(mrow[r], tm);
            alpha[r] = __expf(mrow[r] - nm);
            mrow[r] = nm;
            float s4 = 0.f;
#pragma unroll
            for (int nf = 0; nf < 4; ++nf) {
                const float p = __expf(sc[nf][r] - nm);
                ps[nf][r] = p;
                s4 += p;
            }
#pragma unroll
            for (int off = 1; off < 16; off <<= 1)
                s4 += __shfl_xor(s4, off, 64);
            rsum[r] = s4;
        }
#pragma unroll
        for (int nf2 = 0; nf2 < 2; ++nf2)
#pragma unroll
            for (int r = 0; r < 4; ++r) o[nf2][r] *= alpha[r];
#pragma unroll
        for (int r = 0; r < 4; ++r) lsum[r] = lsum[r] * alpha[r] + rsum[r];
        // P -> per-wave LDS (C-layout scatter), read back as A-frags
#pragma unroll
        for (int nf = 0; nf < 4; ++nf)
#pragma unroll
            for (int r = 0; r < 4; ++r)
                Pw[(quad * 4 + r) * 72 + nf * 16 + lrow] = f2b(ps[nf][r]);
#pragma unroll
        for (int kh = 0; kh < 2; ++kh) {
            bf16x8 pa = *(const bf16x8*)&Pw[lrow * 72 + kh * 32 + quad * 8];
#pragma unroll
            for (int nf2 = 0; nf2 < 2; ++nf2) {
                const int d = nf2 * 16 + lrow;
                bf16x8 vb = *(const bf16x8*)&VT[((int64_t)bh * 32 + d) * VLD + s0 + kh * 32 + quad * 8];
                o[nf2] = __builtin_amdgcn_mfma_f32_16x16x32_bf16(pa, vb, o[nf2], 0, 0, 0);
            }
        }
    }
#pragma unroll
    for (int r = 0; r < 4; ++r) {
        const int q = q0 + quad * 4 + r;
        if (q < 900) {
            const float inv = 1.f / lsum[r];
#pragma unroll
            for (int nf2 = 0; nf2 < 2; ++nf2)
                attno[((int64_t)(b * 900 + q)) * 256 + h * 32 + nf2 * 16 + lrow] = f2b(o[nf2][r] * inv);
        }
    }
}

// ---------------------------------------------------------------------------
// Residual + LayerNorm over C=256, one block per (b,t).
// MODE 0: res = query (B,C,PQ) fp32 transposed-read; out q1 fp32 + q1b bf16
// MODE 1: res = q1 fp32 (BT,C);                      out q2nb bf16 only
// MODE 2: res = q2nb bf16 (BT,C);                    out d_out fp32 (B,C,PQ)
// ---------------------------------------------------------------------------
template <int MODE>
__launch_bounds__(256)
__global__ void ln_kernel(const float* __restrict__ y, const void* __restrict__ res,
                          const float* __restrict__ g, const float* __restrict__ be,
                          float* __restrict__ out_f, short* __restrict__ out_b)
{
    const int bt = blockIdx.x;
    const int b = bt / PQ_, t = bt % PQ_;
    const int c = threadIdx.x;

    float r;
    if (MODE == 0)      r = ((const float*)res)[((int64_t)b * C_ + c) * PQ_ + t];
    else if (MODE == 1) r = ((const float*)res)[(int64_t)bt * C_ + c];
    else                r = b2f(((const short*)res)[(int64_t)bt * C_ + c]);
    const float v = r + y[(int64_t)bt * C_ + c];

    __shared__ float s1[256], s2[256];
    s1[c] = v; s2[c] = v * v;
    __syncthreads();
    for (int st = 128; st > 0; st >>= 1) {
        if (c < st) { s1[c] += s1[c + st]; s2[c] += s2[c + st]; }
        __syncthreads();
    }
    const float mean = s1[0] * (1.f / C_);
    const float var  = s2[0] * (1.f / C_) - mean * mean;
    const float o = (v - mean) * rsqrtf(var + 1e-5f) * g[c] + be[c];

    if (MODE == 0) { out_f[(int64_t)bt * C_ + c] = o; out_b[(int64_t)bt * C_ + c] = f2b(o); }
    else if (MODE == 1) out_b[(int64_t)bt * C_ + c] = f2b(o);
    else out_f[((int64_t)b * C_ + c) * PQ_ + t] = o;
}

// ---------------------------------------------------------------------------
// MS-deformable sampling for one level, accumulating into samp (bf16).
// ---------------------------------------------------------------------------
template <bool INIT>
__launch_bounds__(256)
__global__ void deform_level_kernel(const float* __restrict__ offb, const float* __restrict__ awl,
                                    const float* __restrict__ refp, const short* __restrict__ value_l,
                                    short* __restrict__ samp, int l, int Hl, int Wl)
{
    const int bt = blockIdx.x;
    const int b = bt / PQ_;
    const int tid = threadIdx.x;
    const int h = tid >> 5, d = tid & 31;

    __shared__ float Loff[64];
    __shared__ float Law[128];
    __shared__ float Lref[2];

    if (tid < 64) {
        const int hh = tid >> 3, r = tid & 7;
        Loff[tid] = offb[(int64_t)bt * 256 + hh * 32 + l * 8 + r];
    }
    if (tid < 128) Law[tid] = awl[(int64_t)bt * 128 + tid];
    if (tid < 2)   Lref[tid] = refp[(int64_t)bt * 8 + l * 2 + tid];
    __syncthreads();

    float m = -1e30f;
#pragma unroll
    for (int i = 0; i < 16; ++i) m = fmaxf(m, Law[h * 16 + i]);
    float s = 0.f;
#pragma unroll
    for (int i = 0; i < 16; ++i) s += __expf(Law[h * 16 + i] - m);
    const float invs = 1.f / s;

    const float fx = Lref[0], fy = Lref[1];
    const int HW = Hl * Wl;

    float acc = 0.f;
#pragma unroll
    for (int p = 0; p < P_; ++p) {
        const float ox = Loff[h * 8 + p * 2 + 0];
        const float oy = Loff[h * 8 + p * 2 + 1];
        const float x = (fx + ox / (float)Wl) * (float)Wl - 0.5f;
        const float y = (fy + oy / (float)Hl) * (float)Hl - 0.5f;
        const float x0f = floorf(x), y0f = floorf(y);
        const int x0 = (int)x0f, y0 = (int)y0f;
        const float lw = x - x0f, lh = y - y0f;
        const float w00 = (1.f - lw) * (1.f - lh), w10 = lw * (1.f - lh);
        const float w01 = (1.f - lw) * lh,         w11 = lw * lh;
        const float aww = __expf(Law[h * 16 + l * 4 + p] - m) * invs;

        float sv = 0.f;
        int ix, iy; float w;
#pragma unroll
        for (int cidx = 0; cidx < 4; ++cidx) {
            if (cidx == 0) { ix = x0;     iy = y0;     w = w00; }
            if (cidx == 1) { ix = x0 + 1; iy = y0;     w = w10; }
            if (cidx == 2) { ix = x0;     iy = y0 + 1; w = w01; }
            if (cidx == 3) { ix = x0 + 1; iy = y0 + 1; w = w11; }
            if (ix >= 0 && ix < Wl && iy >= 0 && iy < Hl) {
                const int64_t vi = (((int64_t)b * HW + iy * Wl + ix) * NH_ + h) * DH_ + d;
                sv += w * b2f(value_l[vi]);
            }
        }
        acc += sv * aww;
    }
    const int64_t oi = (int64_t)bt * 256 + tid;
    if (INIT) samp[oi] = f2b(acc);
    else      samp[oi] = f2b(b2f(samp[oi]) + acc);
}

// ---------------------------------------------------------------------------
extern "C" void kernel_launch(void* const* d_in, const int* in_sizes, int n_in,
                              void* d_out, int out_size, void* d_ws, size_t ws_size,
                              hipStream_t stream)
{
    const float* query = (const float*)d_in[0];
    const float* key   = (const float*)d_in[1];
    const float* refp  = (const float*)d_in[4];
    const float* W_in  = (const float*)d_in[5];
    const float* b_in  = (const float*)d_in[6];
    const float* W_out = (const float*)d_in[7];
    const float* b_out = (const float*)d_in[8];
    const float* W_off = (const float*)d_in[9];
    const float* b_off = (const float*)d_in[10];
    const float* W_aw  = (const float*)d_in[11];
    const float* b_aw  = (const float*)d_in[12];
    const float* W_v   = (const float*)d_in[13];
    const float* b_v   = (const float*)d_in[14];
    const float* W_o   = (const float*)d_in[15];
    const float* b_o   = (const float*)d_in[16];
    const float* W1    = (const float*)d_in[17];
    const float* b1    = (const float*)d_in[18];
    const float* W2    = (const float*)d_in[19];
    const float* b2    = (const float*)d_in[20];
    const float* g1    = (const float*)d_in[21];
    const float* be1   = (const float*)d_in[22];
    const float* g2    = (const float*)d_in[23];
    const float* be2   = (const float*)d_in[24];
    const float* g3    = (const float*)d_in[25];
    const float* be3   = (const float*)d_in[26];

    // Workspace plan — same 84.4 MB footprint as rounds 3/4 (known good):
    //  X [62,259,200]: {qkv bf16 11.1M | queryT 3.7M | VT 3.9M | attno 3.7M}
    //                  -> per-level valL (<=62.3M) -> ffh 29.5M
    //  Y: proj -> offb -> proj2 -> ffo ; Z1: q1 ; Wa: q1b -> samp ; Wb: awl -> q2nb
    char* X  = (char*)d_ws;
    char* Yb = X + 62259200;
    char* Z1 = Yb + 7372800;
    char* Wa = Z1 + 7372800;
    char* Wb = Wa + 3686400;

    short* qkvb   = (short*)X;                 // (B*900, 768) bf16
    short* queryT = (short*)(X + 11059200);
    short* VT     = (short*)(X + 14745600);    // 64*32*960*2 = 3,932,160
    short* attno  = (short*)(X + 18677760);
    short* valL   = (short*)X;
    short* ffh    = (short*)X;
    float* proj   = (float*)Yb;
    float* offb   = (float*)Yb;
    float* proj2  = (float*)Yb;
    float* ffo    = (float*)Yb;
    float* q1     = (float*)Z1;
    short* q1b    = (short*)Wa;
    short* samp   = (short*)Wa;
    float* awl    = (float*)Wb;
    short* q2nb   = (short*)Wb;

    const int HL[4] = {100, 50, 25, 13};
    const int WL[4] = {152, 76, 38, 19};
    const int ST[4] = {0, 15200, 19000, 19950};

    // 1. queryT = bf16 transpose of query
    transpose_kernel<<<dim3(29, 8, B_), 256, 0, stream>>>(query, queryT, PQ_, PQ_,
                                                          (int64_t)C_ * PQ_, (int64_t)PQ_ * C_);
    // 2. qkv = queryT @ W_in^T + b_in  (bf16 out)
    mfma_launch<1, true, false, true, false, false>(queryT, W_in, b_in, qkvb, 1, 1, B_ * PQ_, 768, 256,
                                                    256, 256, 768, 0, 0, 0, 0, 0, 0, 1.f, stream);
    // 3. VT (zero-padded to 960)
    vt_kernel<<<dim3(30, 64), 256, 0, stream>>>(qkvb, VT);
    // 4. fused flash attention -> attno (bf16)
    attn_fused<<<dim3(15, 64), 256, 0, stream>>>(qkvb, VT, attno);
    // 5. proj = attno @ W_out^T + b_out
    mfma_launch<1, true, false, true, true, false>(attno, W_out, b_out, proj, 1, 1, B_ * PQ_, 256, 256,
                                                   256, 256, 256, 0, 0, 0, 0, 0, 0, 1.f, stream);
    // 6. q1 = LN(x + proj)  (fp32 + bf16)
    ln_kernel<0><<<B_ * PQ_, 256, 0, stream>>>(proj, query, g1, be1, q1, q1b);
    // 7. offsets / attention-weight logits
    mfma_launch<1, true, false, true, true, false>(q1b, W_off, b_off, offb, 1, 1, B_ * PQ_, 256, 256,
                                                   256, 256, 256, 0, 0, 0, 0, 0, 0, 1.f, stream);
    mfma_launch<1, true, false, true, true, false>(q1b, W_aw, b_aw, awl, 1, 1, B_ * PQ_, 128, 256,
                                                   256, 256, 128, 0, 0, 0, 0, 0, 0, 1.f, stream);
    // 8. per level: transpose key slice -> valL; in-place value GEMM (wide, grid.x=1
    //    required for in-place safety); deform accumulate
    for (int l = 0; l < L_; ++l) {
        const int HW = HL[l] * WL[l];
        transpose_kernel<<<dim3((HW + 31) / 32, 8, B_), 256, 0, stream>>>(
            key + ST[l], valL, HW, PK_, (int64_t)C_ * PK_, (int64_t)HW * 256);
        mfma_launch<4, false, false, true, false, false>(valL, W_v, b_v, valL, 8, 1, HW, 256, 256,
                                                         256, 256, 256,
                                                         (int64_t)HW * 256, 0, 0, 0,
                                                         (int64_t)HW * 256, 0, 1.f, stream);
        if (l == 0)
            deform_level_kernel<true ><<<B_ * PQ_, 256, 0, stream>>>(offb, awl, refp, valL, samp, l, HL[l], WL[l]);
        else
            deform_level_kernel<false><<<B_ * PQ_, 256, 0, stream>>>(offb, awl, refp, valL, samp, l, HL[l], WL[l]);
    }
    // 9. proj2 = samp @ W_o^T + b_o
    mfma_launch<1, true, false, true, true, false>(samp, W_o, b_o, proj2, 1, 1, B_ * PQ_, 256, 256,
                                                   256, 256, 256, 0, 0, 0, 0, 0, 0, 1.f, stream);
    // 10. q2nb = LN(q1 + proj2)  (bf16)
    ln_kernel<1><<<B_ * PQ_, 256, 0, stream>>>(proj2, q1, g2, be2, nullptr, q2nb);
    // 11. ffh = relu(q2nb @ W1^T + b1)  (bf16)
    mfma_launch<1, true, false, true, false, true>(q2nb, W1, b1, ffh, 1, 1, B_ * PQ_, FF_, 256,
                                                   256, 256, FF_, 0, 0, 0, 0, 0, 0, 1.f, stream);
    // 12. ffo = ffh @ W2^T + b2
    mfma_launch<1, true, false, true, true, false>(ffh, W2, b2, ffo, 1, 1, B_ * PQ_, 256, FF_,
                                                   FF_, FF_, 256, 0, 0, 0, 0, 0, 0, 1.f, stream);
    // 13. d_out = LN(q2nb + ffo), transposed to (B,C,PQ)
    ln_kernel<2><<<B_ * PQ_, 256, 0, stream>>>(ffo, q2nb, g3, be3, (float*)d_out, nullptr);

    (void)in_sizes; (void)n_in; (void)out_size; (void)ws_size;
}